// Round 14
// baseline (274.139 us; speedup 1.0000x reference)
//
#include <hip/hip_runtime.h>
#include <cstdint>
#include <cstddef>

using short8 = __attribute__((ext_vector_type(8))) short;
using f32x4  = __attribute__((ext_vector_type(4))) float;
using f32x16 = __attribute__((ext_vector_type(16))) float;
using u16x4  = __attribute__((ext_vector_type(4))) unsigned short;

#define DEV __device__ __forceinline__

DEV unsigned short f2bf(float f) {
  unsigned int u = __builtin_bit_cast(unsigned int, f);
  u += 0x7fffu + ((u >> 16) & 1u);          // RNE
  return (unsigned short)(u >> 16);
}
DEV float bf2f(unsigned short h) {
  unsigned int u = ((unsigned int)h) << 16;
  return __builtin_bit_cast(float, u);
}
DEV unsigned int cvtpk_bf16(float lo, float hi) {  // d.lo16=bf16(lo), d.hi16=bf16(hi)
  unsigned int d;
  asm("v_cvt_pk_bf16_f32 %0, %1, %2" : "=v"(d) : "v"(lo), "v"(hi));
  return d;
}

// direct global->LDS, width 16B (m97 lever). LDS dest = wave-uniform base + lane*16.
#define GLL16(gp, lp)                                                          \
  __builtin_amdgcn_global_load_lds(                                            \
      (const __attribute__((address_space(1))) char*)(const char*)(gp),        \
      (__attribute__((address_space(3))) char*)(char*)(lp), 16, 0, 0)

constexpr int BATCH = 2, SEQ = 2048, DMODEL = 2048, NH = 16, NKVH = 4, DH = 128;
constexpr int MROWS = BATCH * SEQ;            // 4096
constexpr int NQKV  = DMODEL + 2 * NKVH * DH; // 3072 (Q | K | V)
constexpr int KOFF  = DMODEL;                 // 2048
constexpr int VOFF  = DMODEL + NKVH * DH;     // 2560
constexpr float SM_L2 = 0.12751388158f;       // (1/sqrt(128)) * log2(e), folded into Q

// ---------------- prep kernels ----------------

// fused: x fp32 -> bf16 cast (all blocks) + RoPE cos/sin tables (first 512 blocks)
__global__ void k_prep(const float* __restrict__ x, unsigned short* __restrict__ xb,
                       float* __restrict__ tc, float* __restrict__ ts) {
  int id = blockIdx.x * 256 + threadIdx.x;    // MROWS*DMODEL/4 total
  if (id < SEQ * 64) {
    int pos = id >> 6, i = id & 63;
    float freq = __expf(-(float)i * 0.14391157f);
    float ang = (float)pos * freq;
    tc[id] = cosf(ang);
    ts[id] = sinf(ang);
  }
  float4 v = ((const float4*)x)[id];
  u16x4 o = { f2bf(v.x), f2bf(v.y), f2bf(v.z), f2bf(v.w) };
  ((u16x4*)xb)[id] = o;
}

// all 4 weight transposes in one launch: z=0 wq->wT, z=1 wo->woT, z=2 wk, z=3 wv
__global__ __launch_bounds__(256) void k_wtrans4(
    const float* __restrict__ wq, const float* __restrict__ wk,
    const float* __restrict__ wv, const float* __restrict__ wo,
    unsigned short* __restrict__ wT, unsigned short* __restrict__ woT) {
  __shared__ float tile[32][33];
  const int z = blockIdx.z;
  const float* src; unsigned short* dst; int N;
  if (z == 0)      { src = wq; dst = wT;                        N = 2048; }
  else if (z == 1) { src = wo; dst = woT;                       N = 2048; }
  else if (z == 2) { src = wk; dst = wT + (size_t)KOFF * 2048;  N = 512; }
  else             { src = wv; dst = wT + (size_t)VOFF * 2048;  N = 512; }
  int n0 = blockIdx.x * 32, k0 = blockIdx.y * 32;
  if (n0 >= N) return;
  int tx = threadIdx.x, ty = threadIdx.y;     // 32 x 8
  #pragma unroll
  for (int r = ty; r < 32; r += 8)
    tile[r][tx] = src[(size_t)(k0 + r) * N + n0 + tx];
  __syncthreads();
  #pragma unroll
  for (int r = ty; r < 32; r += 8)
    dst[(size_t)(n0 + r) * 2048 + k0 + tx] = f2bf(tile[tx][r]);
}

// V region of qkv -> vt[b][kvh][d=128][s=2048]  (bf16 -> bf16 transpose)
__global__ __launch_bounds__(256) void k_vtrans(const unsigned short* __restrict__ qkv,
                                                unsigned short* __restrict__ vt) {
  __shared__ unsigned short tile[32][33];
  int s0 = blockIdx.x * 32, d0 = blockIdx.y * 32;
  int bk = blockIdx.z;                         // b*4 + kvh
  const unsigned short* src = qkv + (size_t)(bk >> 2) * SEQ * NQKV + VOFF + (bk & 3) * DH;
  unsigned short* dst = vt + ((size_t)bk * DH + d0) * SEQ + s0;
  int tx = threadIdx.x, ty = threadIdx.y;      // 32 x 8
  #pragma unroll
  for (int r = ty; r < 32; r += 8)
    tile[r][tx] = src[(size_t)(s0 + r) * NQKV + d0 + tx];
  __syncthreads();
  #pragma unroll
  for (int r = ty; r < 32; r += 8)
    dst[(size_t)r * SEQ + tx] = tile[tx][r];
}

// ---------------- big-tile GEMM: C[m][n] = sum_k A[m][k]*Bt[n][k] ------------
// 256xBNT tile (BNT in {128,192,256}), BK=64, 512 thr / 8 waves (2M x 4N),
// double-buffered LDS, counted vmcnt (T3/T4), ^(row&7) chunk swizzle (T2),
// setprio around MFMA clusters (T5). ROPE=true: rotary fused into epilogue.

template <int BNT, bool OUTF32, bool ROPE>
__global__ __launch_bounds__(512, 2) void k_gemm256(
    const unsigned short* __restrict__ A,   // M x K bf16
    const unsigned short* __restrict__ Bt,  // N x K bf16
    void* __restrict__ C, int M, int N, int K,
    const float* __restrict__ tc, const float* __restrict__ ts) {
  constexpr int NF = BNT / 64;              // n-frags per wave (per-wave N = BNT/4)
  __shared__ unsigned short As[2][256 * 64];
  __shared__ unsigned short Bs[2][BNT * 64];

  const int t = threadIdx.x, l = t & 63, w = t >> 6;
  const int rl = l & 15, kg = l >> 4;
  const int wm = w >> 2, wn = w & 3;

  // XCD-aware swizzle (T1): nwg % 8 == 0 for all instantiations
  const int gx = gridDim.x;
  const int nwg = gx * gridDim.y;
  const int idl = blockIdx.y * gx + blockIdx.x;
  const int swz = (idl & 7) * (nwg >> 3) + (idl >> 3);
  const int m0 = (swz / gx) * 256, n0 = (swz % gx) * BNT;

  // staging sources (pre-swizzled: LDS dest linear, source permuted, read XOR'd)
  const unsigned short* aSrc[4];
  const unsigned short* bSrc[NF];
  #pragma unroll
  for (int i = 0; i < 4; ++i) {
    int c = i * 512 + t, row = c >> 3, q = c & 7;
    aSrc[i] = A + (size_t)(m0 + row) * K + ((q ^ (row & 7)) << 3);
  }
  #pragma unroll
  for (int i = 0; i < NF; ++i) {
    int c = i * 512 + t, row = c >> 3, q = c & 7;
    bSrc[i] = Bt + (size_t)(n0 + row) * K + ((q ^ (row & 7)) << 3);
  }

  f32x4 acc[8][NF] = {};

  const int nk = K / 64;
  // prologue: stage K-tile 0 into buffer 0
  #pragma unroll
  for (int i = 0; i < 4; ++i) GLL16(aSrc[i], (char*)As[0] + i * 8192 + t * 16);
  #pragma unroll
  for (int i = 0; i < NF; ++i) GLL16(bSrc[i], (char*)Bs[0] + i * 8192 + t * 16);

  int cur = 0;
  for (int kt = 0; kt < nk; ++kt) {
    if (kt + 1 < nk) {                           // issue next K-tile into buf^1
      const int off = (kt + 1) * 64;
      #pragma unroll
      for (int i = 0; i < 4; ++i)
        GLL16(aSrc[i] + off, (char*)As[cur ^ 1] + i * 8192 + t * 16);
      #pragma unroll
      for (int i = 0; i < NF; ++i)
        GLL16(bSrc[i] + off, (char*)Bs[cur ^ 1] + i * 8192 + t * 16);
      if constexpr (NF == 4)      asm volatile("s_waitcnt vmcnt(8)" ::: "memory");
      else if constexpr (NF == 3) asm volatile("s_waitcnt vmcnt(7)" ::: "memory");
      else                        asm volatile("s_waitcnt vmcnt(6)" ::: "memory");
    } else {
      asm volatile("s_waitcnt vmcnt(0)" ::: "memory");
    }
    __builtin_amdgcn_sched_barrier(0);
    __builtin_amdgcn_s_barrier();                // K-tile kt resident in buf[cur]

    const unsigned short* a = As[cur];
    const unsigned short* b = Bs[cur];
    auto rdA = [&](int mf, int ks) {
      int row = wm * 128 + mf * 16 + rl;
      return *(const short8*)&a[row * 64 + (((ks * 4 + kg) ^ (row & 7)) << 3)];
    };
    auto rdB = [&](int nf, int ks) {
      int row = wn * (BNT / 4) + nf * 16 + rl;
      return *(const short8*)&b[row * 64 + (((ks * 4 + kg) ^ (row & 7)) << 3)];
    };

    short8 aF[4][2], bF[NF][2];
    // A-half0 phases: per n-frag j, read bF[j] then 8 MFMA
    #pragma unroll
    for (int mi = 0; mi < 4; ++mi)
      #pragma unroll
      for (int ks = 0; ks < 2; ++ks) aF[mi][ks] = rdA(mi, ks);
    #pragma unroll
    for (int j = 0; j < NF; ++j) {
      #pragma unroll
      for (int ks = 0; ks < 2; ++ks) bF[j][ks] = rdB(j, ks);
      __builtin_amdgcn_s_setprio(1);
      #pragma unroll
      for (int mi = 0; mi < 4; ++mi)
        #pragma unroll
        for (int ks = 0; ks < 2; ++ks)
          acc[mi][j] = __builtin_amdgcn_mfma_f32_16x16x32_bf16(aF[mi][ks], bF[j][ks], acc[mi][j], 0, 0, 0);
      __builtin_amdgcn_s_setprio(0);
    }
    // A-half1 phases (bF already live)
    #pragma unroll
    for (int mi = 0; mi < 4; ++mi)
      #pragma unroll
      for (int ks = 0; ks < 2; ++ks) aF[mi][ks] = rdA(4 + mi, ks);
    #pragma unroll
    for (int j = 0; j < NF; ++j) {
      __builtin_amdgcn_s_setprio(1);
      #pragma unroll
      for (int mi = 0; mi < 4; ++mi)
        #pragma unroll
        for (int ks = 0; ks < 2; ++ks)
          acc[4 + mi][j] = __builtin_amdgcn_mfma_f32_16x16x32_bf16(aF[mi][ks], bF[j][ks], acc[4 + mi][j], 0, 0, 0);
      __builtin_amdgcn_s_setprio(0);
    }

    __builtin_amdgcn_s_barrier();                // all waves done reading buf[cur]
    cur ^= 1;
  }

  // epilogue; C/D layout (m89-verified): col = lane&15, row = (lane>>4)*4 + reg
  #pragma unroll
  for (int mf = 0; mf < 8; ++mf) {
    #pragma unroll
    for (int nf = 0; nf < NF; ++nf) {
      const int row0 = m0 + wm * 128 + mf * 16 + kg * 4;
      const int colb = n0 + wn * (BNT / 4) + nf * 16;
      const int col = colb + rl;
      if constexpr (ROPE) {
        if (colb < VOFF) {                       // Q or K region (V untouched)
          const int dd = (col & 127) >> 1;       // pair index within head
          const float sgn = (col & 1) ? 1.0f : -1.0f;
          const float qs = (colb < KOFF) ? SM_L2 : 1.0f;
          #pragma unroll
          for (int r = 0; r < 4; ++r) {
            const int s = (row0 + r) & (SEQ - 1);
            const float c = tc[s * 64 + dd], sn = ts[s * 64 + dd];
            const float xv = acc[mf][nf][r];
            const float xp = __shfl_xor(xv, 1);  // partner column (col^1)
            acc[mf][nf][r] = (xv * c + sgn * xp * sn) * qs;
          }
        }
      }
      #pragma unroll
      for (int r = 0; r < 4; ++r) {
        if constexpr (OUTF32)
          ((float*)C)[(size_t)(row0 + r) * N + col] = acc[mf][nf][r];
        else
          ((unsigned short*)C)[(size_t)(row0 + r) * N + col] = f2bf(acc[mf][nf][r]);
      }
    }
  }
}

// ---------------- flash attention, causal, GQA ------------------------------
// 32x32x16 MFMA version: 8 waves as 4 pairs; pair shares 32 q-rows (QK^T and
// softmax computed redundantly per pair), each wave owns a 64-wide d-half of
// PV. P stays IN REGISTERS via cvt_pk + permlane32_swap (T12) -> LDS = 64KB
// (2 blocks/CU). KVBLK=64 double-buffered via GLL16 + counted vmcnt (T3/T4).

constexpr int QB = 128, KB = 64;
constexpr float THR = 8.0f;                    // defer-max threshold (log2 domain)

__global__ __launch_bounds__(512, 4) void k_attn(const unsigned short* __restrict__ qkv,
                                                 const unsigned short* __restrict__ vt,
                                                 unsigned short* __restrict__ obuf) {
  __shared__ unsigned short Ks[2][KB * DH];     // 2 x [64][128], chunk-XOR ^(row&7)
  __shared__ unsigned short Vs[2][DH * KB];     // 2 x [128][64], chunk-XOR ^(row&7)

  const int t = threadIdx.x, l = t & 63, w = t >> 6;
  const int ql = l & 31;                        // q column (32x32 C-layout)
  const int hi = l >> 5;                        // lane half
  const int wq = w >> 1;                        // q-group 0..3 (wave pair)
  const int dhalf = (w & 1) * 64;               // this wave's PV d-half

  // complementary-pair decode: ids i and i+256 get q-tiles qt and 15-qt
  const int id = blockIdx.x;                    // [0, 512)
  const int b = id >> 8;
  const int u = id & 255;
  const int h = u >> 4;
  const int qtr = u & 15;
  const int qt = b ? (15 - qtr) : qtr;
  const int q0 = qt * QB;
  const int kvh = h >> 2;

  const unsigned short* qbase = qkv + (size_t)b * SEQ * NQKV;
  const unsigned short* kbase = qbase + KOFF + kvh * DH;
  const unsigned short* vtb = vt + (size_t)(b * NKVH + kvh) * DH * SEQ;

  // staging sources: K chunks c=i*512+t (row=c>>4, q=c&15); V chunks (row=c>>3, q=c&7)
  const unsigned short* kp[2];
  const unsigned short* vp[2];
  #pragma unroll
  for (int i = 0; i < 2; ++i) {
    int c = i * 512 + t;
    int krow = c >> 4, kq = c & 15;
    kp[i] = kbase + (size_t)krow * NQKV + ((kq ^ (krow & 7)) << 3);
    int vrow = c >> 3, vq = c & 7;
    vp[i] = vtb + (size_t)vrow * SEQ + ((vq ^ (vrow & 7)) << 3);
  }

  const int qw0 = q0 + wq * 32;                 // pair's 32 q-rows

  // Q fragments (B-operand, 32x32x16): lane holds Q[qw0+ql][ks*16 + hi*8 + j]
  short8 qF[8];
  {
    const size_t qr = (size_t)(qw0 + ql) * NQKV + h * DH;
    #pragma unroll
    for (int ks = 0; ks < 8; ++ks)
      qF[ks] = *(const short8*)(qbase + qr + ks * 16 + hi * 8);
  }

  f32x16 Oc[2] = {};                            // O^T[d=dhalf+cc*32+rows][q=ql]
  float mr = -3e38f, lr = 0.f;                  // per-lane state for q = qw0 + ql

  const int nt = q0 / KB + 2;                   // kv tiles up to (incl.) diagonal

  // prologue: stage tile 0 into buffer 0 (4 GLL16 / wave)
  #pragma unroll
  for (int i = 0; i < 2; ++i) {
    GLL16(kp[i], (char*)Ks[0] + w * 1024 + i * 8192);
    GLL16(vp[i], (char*)Vs[0] + w * 1024 + i * 8192);
  }

  int cur = 0;
  for (int tt = 0; tt < nt; ++tt) {
    const int kv0 = tt * KB;
    const bool more = (tt + 1 < nt);
    if (more) {                                  // issue next-tile loads into buf^1
      #pragma unroll
      for (int i = 0; i < 2; ++i) {
        GLL16(kp[i] + (size_t)(kv0 + KB) * NQKV, (char*)Ks[cur ^ 1] + w * 1024 + i * 8192);
        GLL16(vp[i] + (kv0 + KB),               (char*)Vs[cur ^ 1] + w * 1024 + i * 8192);
      }
      asm volatile("s_waitcnt vmcnt(4)" ::: "memory");   // tile tt's 4 loads landed
    } else {
      asm volatile("s_waitcnt vmcnt(0)" ::: "memory");
    }
    __builtin_amdgcn_sched_barrier(0);
    __builtin_amdgcn_s_barrier();                // all waves' tile-tt loads visible

    if (kv0 < qw0 + 32) {                        // not fully masked (wave-uniform)
      const unsigned short* KsC = Ks[cur];
      const unsigned short* VsC = Vs[cur];

      // S^T = K Q (32x32x16): St[c] covers kv rows kv0+c*32..+31, q cols qw0+ql
      f32x16 St[2] = {};
      __builtin_amdgcn_s_setprio(1);
      #pragma unroll
      for (int c = 0; c < 2; ++c) {
        const int krow = c * 32 + ql;
        #pragma unroll
        for (int ks = 0; ks < 8; ++ks) {
          short8 kF = *(const short8*)&KsC[krow * DH + (((ks * 2 + hi) ^ (krow & 7)) << 3)];
          St[c] = __builtin_amdgcn_mfma_f32_32x32x16_bf16(kF, qF[ks], St[c], 0, 0, 0);
        }
      }
      __builtin_amdgcn_s_setprio(0);

      // mask + max; C row = (r&3) + 8*(r>>2) + 4*hi (m74/m101 layout)
      float mx = -3e38f;
      const bool diag = (kv0 + KB - 1) > qw0;    // tile straddles the diagonal
      if (diag) {
        const int thr = qw0 + ql - kv0;
        #pragma unroll
        for (int c = 0; c < 2; ++c)
          #pragma unroll
          for (int r = 0; r < 16; ++r) {
            const int kvl = c * 32 + (r & 3) + 8 * (r >> 2) + 4 * hi;
            float s = St[c][r];
            if (kvl > thr) s = -3e38f;
            St[c][r] = s;
            mx = fmaxf(mx, s);
          }
      } else {
        #pragma unroll
        for (int c = 0; c < 2; ++c)
          #pragma unroll
          for (int r = 0; r < 16; ++r) mx = fmaxf(mx, St[c][r]);
      }
      mx = fmaxf(mx, __shfl_xor(mx, 32));        // lanes l, l^32 share q

      // deferred rescale (T13) — sf is per-lane (per-q), no broadcast needed
      if (__any(mx > mr + THR)) {
        const float mnew = fmaxf(mr, mx);
        const float sf = exp2f(mr - mnew);
        mr = mnew;
        lr *= sf;
        #pragma unroll
        for (int cc = 0; cc < 2; ++cc)
          #pragma unroll
          for (int r = 0; r < 16; ++r) Oc[cc][r] *= sf;
      }

      // exp2 (in place) + lane-local sum
      float rs = 0.f;
      #pragma unroll
      for (int c = 0; c < 2; ++c)
        #pragma unroll
        for (int r = 0; r < 16; ++r) {
          float e = exp2f(St[c][r] - mr);
          St[c][r] = e;
          rs += e;
        }
      rs += __shfl_xor(rs, 32);
      lr += rs;

      // build PV B-frags in registers: per (c,s) 16-kv step, 4 cvt_pk + 2
      // permlane32_swap produce words (kv+0,1),(+2,3),(+4,5),(+6,7) for both
      // lane halves (lo needs kv base+0..7, hi needs base+8..15).
      short8 pB[4];
      #pragma unroll
      for (int c = 0; c < 2; ++c)
        #pragma unroll
        for (int s = 0; s < 2; ++s) {
          unsigned int X0 = cvtpk_bf16(St[c][s * 8 + 0], St[c][s * 8 + 1]);
          unsigned int X1 = cvtpk_bf16(St[c][s * 8 + 2], St[c][s * 8 + 3]);
          unsigned int X2 = cvtpk_bf16(St[c][s * 8 + 4], St[c][s * 8 + 5]);
          unsigned int X3 = cvtpk_bf16(St[c][s * 8 + 6], St[c][s * 8 + 7]);
          asm("v_permlane32_swap_b32 %0, %1" : "+v"(X0), "+v"(X2));
          asm("v_permlane32_swap_b32 %0, %1" : "+v"(X1), "+v"(X3));
          uint4 uw = { X0, X1, X2, X3 };
          pB[c * 2 + s] = __builtin_bit_cast(short8, uw);
        }

      // PV (32x32x16): O^T[d][q] += V^T[d][kv] P^T[kv][q]; A = V^T from Vs
      __builtin_amdgcn_s_setprio(1);
      #pragma unroll
      for (int cc = 0; cc < 2; ++cc) {
        const int vrow = dhalf + cc * 32 + ql;
        #pragma unroll
        for (int ks2 = 0; ks2 < 4; ++ks2) {
          short8 vF = *(const short8*)&VsC[vrow * KB + (((ks2 * 2 + hi) ^ (vrow & 7)) << 3)];
          Oc[cc] = __builtin_amdgcn_mfma_f32_32x32x16_bf16(vF, pB[ks2], Oc[cc], 0, 0, 0);
        }
      }
      __builtin_amdgcn_s_setprio(0);
    }

    __builtin_amdgcn_s_barrier();                // all waves done reading buf[cur]
    cur ^= 1;
  }

  // epilogue: O /= l; lane writes q-row qw0+ql, d = dhalf+cc*32+8*rq+4*hi+i
  const float linv = 1.0f / lr;
  const size_t rowb = (size_t)(b * SEQ + qw0 + ql) * DMODEL + h * DH + dhalf;
  #pragma unroll
  for (int cc = 0; cc < 2; ++cc)
    #pragma unroll
    for (int rq = 0; rq < 4; ++rq) {
      uint2 dwords;
      dwords.x = cvtpk_bf16(Oc[cc][rq * 4 + 0] * linv, Oc[cc][rq * 4 + 1] * linv);
      dwords.y = cvtpk_bf16(Oc[cc][rq * 4 + 2] * linv, Oc[cc][rq * 4 + 3] * linv);
      *(uint2*)&obuf[rowb + cc * 32 + 8 * rq + 4 * hi] = dwords;
    }
}

// ---------------- launch ----------------------------------------------------

extern "C" void kernel_launch(void* const* d_in, const int* in_sizes, int n_in,
                              void* d_out, int out_size, void* d_ws, size_t ws_size,
                              hipStream_t stream) {
  const float* x  = (const float*)d_in[0];
  const float* wq = (const float*)d_in[1];
  const float* wk = (const float*)d_in[2];
  const float* wv = (const float*)d_in[3];
  const float* wo = (const float*)d_in[4];
  float* out = (float*)d_out;

  unsigned short* xb  = (unsigned short*)d_ws;                 // 4096x2048
  unsigned short* wT  = xb  + (size_t)MROWS * DMODEL;          // 3072x2048 (q|k|v transposed)
  unsigned short* woT = wT  + (size_t)NQKV * DMODEL;           // 2048x2048
  unsigned short* qkv = woT + (size_t)DMODEL * DMODEL;         // 4096x3072
  unsigned short* ob  = qkv + (size_t)MROWS * NQKV;            // 4096x2048
  float* tc = (float*)(ob + (size_t)MROWS * DMODEL);           // 2048x64
  float* ts = tc + SEQ * 64;
  // vt reuses the wT region (wT dead after the QKV GEMM)
  unsigned short* vtG = wT;

  k_prep<<<dim3(MROWS * DMODEL / 4 / 256), dim3(256), 0, stream>>>(x, xb, tc, ts);
  k_wtrans4<<<dim3(64, 64, 4), dim3(32, 8), 0, stream>>>(wq, wk, wv, wo, wT, woT);

  // QKV: 4096x3072 = (16 x 16) tiles of 256x192 -> exactly 1 block/CU, no tail
  k_gemm256<192, false, true><<<dim3(NQKV / 192, MROWS / 256), dim3(512), 0, stream>>>(
      xb, wT, qkv, MROWS, NQKV, DMODEL, tc, ts);
  k_vtrans<<<dim3(SEQ / 32, DH / 32, BATCH * NKVH), dim3(32, 8), 0, stream>>>(qkv, vtG);
  k_attn<<<dim3(512), dim3(512), 0, stream>>>(qkv, vtG, ob);
  k_gemm256<128, true, false><<<dim3(DMODEL / 128, MROWS / 256), dim3(512), 0, stream>>>(
      ob, woT, out, MROWS, DMODEL, DMODEL, nullptr, nullptr);
}

// Round 15
// 212.433 us; speedup vs baseline: 1.2905x; 1.2905x over previous
//
#include <hip/hip_runtime.h>
#include <cstdint>
#include <cstddef>

using short8 = __attribute__((ext_vector_type(8))) short;
using f32x4  = __attribute__((ext_vector_type(4))) float;
using u16x4  = __attribute__((ext_vector_type(4))) unsigned short;

#define DEV __device__ __forceinline__

DEV unsigned short f2bf(float f) {
  unsigned int u = __builtin_bit_cast(unsigned int, f);
  u += 0x7fffu + ((u >> 16) & 1u);          // RNE
  return (unsigned short)(u >> 16);
}
DEV float bf2f(unsigned short h) {
  unsigned int u = ((unsigned int)h) << 16;
  return __builtin_bit_cast(float, u);
}
DEV unsigned int cvtpk_bf16(float lo, float hi) {  // d.lo16=bf16(lo), d.hi16=bf16(hi)
  unsigned int d;
  asm("v_cvt_pk_bf16_f32 %0, %1, %2" : "=v"(d) : "v"(lo), "v"(hi));
  return d;
}

// direct global->LDS, width 16B (m97 lever). LDS dest = wave-uniform base + lane*16.
#define GLL16(gp, lp)                                                          \
  __builtin_amdgcn_global_load_lds(                                            \
      (const __attribute__((address_space(1))) char*)(const char*)(gp),        \
      (__attribute__((address_space(3))) char*)(char*)(lp), 16, 0, 0)

constexpr int BATCH = 2, SEQ = 2048, DMODEL = 2048, NH = 16, NKVH = 4, DH = 128;
constexpr int MROWS = BATCH * SEQ;            // 4096
constexpr int NQKV  = DMODEL + 2 * NKVH * DH; // 3072 (Q | K | V)
constexpr int KOFF  = DMODEL;                 // 2048
constexpr int VOFF  = DMODEL + NKVH * DH;     // 2560
constexpr float SM_L2 = 0.12751388158f;       // (1/sqrt(128)) * log2(e), folded into Q

// ---------------- prep kernels ----------------

// fused: x fp32 -> bf16 cast (all blocks) + RoPE cos/sin tables (first 512 blocks)
__global__ void k_prep(const float* __restrict__ x, unsigned short* __restrict__ xb,
                       float* __restrict__ tc, float* __restrict__ ts) {
  int id = blockIdx.x * 256 + threadIdx.x;    // MROWS*DMODEL/4 total
  if (id < SEQ * 64) {
    int pos = id >> 6, i = id & 63;
    float freq = __expf(-(float)i * 0.14391157f);
    float ang = (float)pos * freq;
    tc[id] = cosf(ang);
    ts[id] = sinf(ang);
  }
  float4 v = ((const float4*)x)[id];
  u16x4 o = { f2bf(v.x), f2bf(v.y), f2bf(v.z), f2bf(v.w) };
  ((u16x4*)xb)[id] = o;
}

// all 4 weight transposes in one launch: z=0 wq->wT, z=1 wo->woT, z=2 wk, z=3 wv
__global__ __launch_bounds__(256) void k_wtrans4(
    const float* __restrict__ wq, const float* __restrict__ wk,
    const float* __restrict__ wv, const float* __restrict__ wo,
    unsigned short* __restrict__ wT, unsigned short* __restrict__ woT) {
  __shared__ float tile[32][33];
  const int z = blockIdx.z;
  const float* src; unsigned short* dst; int N;
  if (z == 0)      { src = wq; dst = wT;                        N = 2048; }
  else if (z == 1) { src = wo; dst = woT;                       N = 2048; }
  else if (z == 2) { src = wk; dst = wT + (size_t)KOFF * 2048;  N = 512; }
  else             { src = wv; dst = wT + (size_t)VOFF * 2048;  N = 512; }
  int n0 = blockIdx.x * 32, k0 = blockIdx.y * 32;
  if (n0 >= N) return;
  int tx = threadIdx.x, ty = threadIdx.y;     // 32 x 8
  #pragma unroll
  for (int r = ty; r < 32; r += 8)
    tile[r][tx] = src[(size_t)(k0 + r) * N + n0 + tx];
  __syncthreads();
  #pragma unroll
  for (int r = ty; r < 32; r += 8)
    dst[(size_t)(n0 + r) * 2048 + k0 + tx] = f2bf(tile[tx][r]);
}

// V region of qkv -> vt[b][kvh][d=128][s=2048]  (bf16 -> bf16 transpose)
__global__ __launch_bounds__(256) void k_vtrans(const unsigned short* __restrict__ qkv,
                                                unsigned short* __restrict__ vt) {
  __shared__ unsigned short tile[32][33];
  int s0 = blockIdx.x * 32, d0 = blockIdx.y * 32;
  int bk = blockIdx.z;                         // b*4 + kvh
  const unsigned short* src = qkv + (size_t)(bk >> 2) * SEQ * NQKV + VOFF + (bk & 3) * DH;
  unsigned short* dst = vt + ((size_t)bk * DH + d0) * SEQ + s0;
  int tx = threadIdx.x, ty = threadIdx.y;      // 32 x 8
  #pragma unroll
  for (int r = ty; r < 32; r += 8)
    tile[r][tx] = src[(size_t)(s0 + r) * NQKV + d0 + tx];
  __syncthreads();
  #pragma unroll
  for (int r = ty; r < 32; r += 8)
    dst[(size_t)r * SEQ + tx] = tile[tx][r];
}

// ---------------- big-tile GEMM: C[m][n] = sum_k A[m][k]*Bt[n][k] ------------
// 256xBNT tile (BNT in {128,192,256}), BK=64, 512 thr / 8 waves (2M x 4N),
// double-buffered LDS, counted vmcnt (T3/T4), ^(row&7) chunk swizzle (T2),
// setprio around MFMA clusters (T5). ROPE=true: rotary fused into epilogue.

template <int BNT, bool OUTF32, bool ROPE>
__global__ __launch_bounds__(512, 2) void k_gemm256(
    const unsigned short* __restrict__ A,   // M x K bf16
    const unsigned short* __restrict__ Bt,  // N x K bf16
    void* __restrict__ C, int M, int N, int K,
    const float* __restrict__ tc, const float* __restrict__ ts) {
  constexpr int NF = BNT / 64;              // n-frags per wave (per-wave N = BNT/4)
  __shared__ unsigned short As[2][256 * 64];
  __shared__ unsigned short Bs[2][BNT * 64];

  const int t = threadIdx.x, l = t & 63, w = t >> 6;
  const int rl = l & 15, kg = l >> 4;
  const int wm = w >> 2, wn = w & 3;

  // XCD-aware swizzle (T1): nwg % 8 == 0 for all instantiations
  const int gx = gridDim.x;
  const int nwg = gx * gridDim.y;
  const int idl = blockIdx.y * gx + blockIdx.x;
  const int swz = (idl & 7) * (nwg >> 3) + (idl >> 3);
  const int m0 = (swz / gx) * 256, n0 = (swz % gx) * BNT;

  // staging sources (pre-swizzled: LDS dest linear, source permuted, read XOR'd)
  const unsigned short* aSrc[4];
  const unsigned short* bSrc[NF];
  #pragma unroll
  for (int i = 0; i < 4; ++i) {
    int c = i * 512 + t, row = c >> 3, q = c & 7;
    aSrc[i] = A + (size_t)(m0 + row) * K + ((q ^ (row & 7)) << 3);
  }
  #pragma unroll
  for (int i = 0; i < NF; ++i) {
    int c = i * 512 + t, row = c >> 3, q = c & 7;
    bSrc[i] = Bt + (size_t)(n0 + row) * K + ((q ^ (row & 7)) << 3);
  }

  f32x4 acc[8][NF] = {};

  const int nk = K / 64;
  // prologue: stage K-tile 0 into buffer 0
  #pragma unroll
  for (int i = 0; i < 4; ++i) GLL16(aSrc[i], (char*)As[0] + i * 8192 + t * 16);
  #pragma unroll
  for (int i = 0; i < NF; ++i) GLL16(bSrc[i], (char*)Bs[0] + i * 8192 + t * 16);

  int cur = 0;
  for (int kt = 0; kt < nk; ++kt) {
    if (kt + 1 < nk) {                           // issue next K-tile into buf^1
      const int off = (kt + 1) * 64;
      #pragma unroll
      for (int i = 0; i < 4; ++i)
        GLL16(aSrc[i] + off, (char*)As[cur ^ 1] + i * 8192 + t * 16);
      #pragma unroll
      for (int i = 0; i < NF; ++i)
        GLL16(bSrc[i] + off, (char*)Bs[cur ^ 1] + i * 8192 + t * 16);
      if constexpr (NF == 4)      asm volatile("s_waitcnt vmcnt(8)" ::: "memory");
      else if constexpr (NF == 3) asm volatile("s_waitcnt vmcnt(7)" ::: "memory");
      else                        asm volatile("s_waitcnt vmcnt(6)" ::: "memory");
    } else {
      asm volatile("s_waitcnt vmcnt(0)" ::: "memory");
    }
    __builtin_amdgcn_sched_barrier(0);
    __builtin_amdgcn_s_barrier();                // K-tile kt resident in buf[cur]

    const unsigned short* a = As[cur];
    const unsigned short* b = Bs[cur];
    auto rdA = [&](int mf, int ks) {
      int row = wm * 128 + mf * 16 + rl;
      return *(const short8*)&a[row * 64 + (((ks * 4 + kg) ^ (row & 7)) << 3)];
    };
    auto rdB = [&](int nf, int ks) {
      int row = wn * (BNT / 4) + nf * 16 + rl;
      return *(const short8*)&b[row * 64 + (((ks * 4 + kg) ^ (row & 7)) << 3)];
    };

    short8 aF[4][2], bF[NF][2];
    // A-half0 phases: per n-frag j, read bF[j] then 8 MFMA
    #pragma unroll
    for (int mi = 0; mi < 4; ++mi)
      #pragma unroll
      for (int ks = 0; ks < 2; ++ks) aF[mi][ks] = rdA(mi, ks);
    #pragma unroll
    for (int j = 0; j < NF; ++j) {
      #pragma unroll
      for (int ks = 0; ks < 2; ++ks) bF[j][ks] = rdB(j, ks);
      __builtin_amdgcn_s_setprio(1);
      #pragma unroll
      for (int mi = 0; mi < 4; ++mi)
        #pragma unroll
        for (int ks = 0; ks < 2; ++ks)
          acc[mi][j] = __builtin_amdgcn_mfma_f32_16x16x32_bf16(aF[mi][ks], bF[j][ks], acc[mi][j], 0, 0, 0);
      __builtin_amdgcn_s_setprio(0);
    }
    // A-half1 phases (bF already live)
    #pragma unroll
    for (int mi = 0; mi < 4; ++mi)
      #pragma unroll
      for (int ks = 0; ks < 2; ++ks) aF[mi][ks] = rdA(4 + mi, ks);
    #pragma unroll
    for (int j = 0; j < NF; ++j) {
      __builtin_amdgcn_s_setprio(1);
      #pragma unroll
      for (int mi = 0; mi < 4; ++mi)
        #pragma unroll
        for (int ks = 0; ks < 2; ++ks)
          acc[4 + mi][j] = __builtin_amdgcn_mfma_f32_16x16x32_bf16(aF[mi][ks], bF[j][ks], acc[4 + mi][j], 0, 0, 0);
      __builtin_amdgcn_s_setprio(0);
    }

    __builtin_amdgcn_s_barrier();                // all waves done reading buf[cur]
    cur ^= 1;
  }

  // epilogue; C/D layout (m89-verified): col = lane&15, row = (lane>>4)*4 + reg
  #pragma unroll
  for (int mf = 0; mf < 8; ++mf) {
    #pragma unroll
    for (int nf = 0; nf < NF; ++nf) {
      const int row0 = m0 + wm * 128 + mf * 16 + kg * 4;
      const int colb = n0 + wn * (BNT / 4) + nf * 16;
      const int col = colb + rl;
      if constexpr (ROPE) {
        if (colb < VOFF) {                       // Q or K region (V untouched)
          const int dd = (col & 127) >> 1;       // pair index within head
          const float sgn = (col & 1) ? 1.0f : -1.0f;
          const float qs = (colb < KOFF) ? SM_L2 : 1.0f;
          #pragma unroll
          for (int r = 0; r < 4; ++r) {
            const int s = (row0 + r) & (SEQ - 1);
            const float c = tc[s * 64 + dd], sn = ts[s * 64 + dd];
            const float xv = acc[mf][nf][r];
            const float xp = __shfl_xor(xv, 1);  // partner column (col^1)
            acc[mf][nf][r] = (xv * c + sgn * xp * sn) * qs;
          }
        }
      }
      #pragma unroll
      for (int r = 0; r < 4; ++r) {
        if constexpr (OUTF32)
          ((float*)C)[(size_t)(row0 + r) * N + col] = acc[mf][nf][r];
        else
          ((unsigned short*)C)[(size_t)(row0 + r) * N + col] = f2bf(acc[mf][nf][r]);
      }
    }
  }
}

// ---------------- flash attention, causal, GQA ------------------------------
// 8 waves x 16 q-rows (QB=128), KVBLK=64 DOUBLE-BUFFERED via GLL16 with counted
// vmcnt(4) + raw barriers (T3/T4); swapped QK^T -> lane-local softmax; P in LDS
// at stride 64 with XOR swizzle (write/read same key) -> total LDS exactly 80KB.

constexpr int QB = 128, KB = 64;
constexpr float THR = 8.0f;                    // defer-max threshold (log2 domain)

__global__ __launch_bounds__(512, 4) void k_attn(const unsigned short* __restrict__ qkv,
                                                 const unsigned short* __restrict__ vt,
                                                 unsigned short* __restrict__ obuf) {
  __shared__ unsigned short Ks[2][KB * DH];     // 2 x [64][128], chunk-XOR ^(row&7)
  __shared__ unsigned short Vs[2][DH * KB];     // 2 x [128][64], chunk-XOR ^(row&7)
  __shared__ unsigned short Pw[8][16 * 64];     // per-wave P, stride 64, XOR ^(rl&7)<<4

  const int t = threadIdx.x, l = t & 63, w = t >> 6;
  const int rl = l & 15, kg = l >> 4;

  // complementary-pair decode: ids i and i+256 get q-tiles qt and 15-qt
  const int id = blockIdx.x;                    // [0, 512)
  const int b = id >> 8;
  const int u = id & 255;
  const int h = u >> 4;
  const int qtr = u & 15;
  const int qt = b ? (15 - qtr) : qtr;
  const int q0 = qt * QB;
  const int kvh = h >> 2;

  const unsigned short* qbase = qkv + (size_t)b * SEQ * NQKV;
  const unsigned short* kbase = qbase + KOFF + kvh * DH;
  const unsigned short* vtb = vt + (size_t)(b * NKVH + kvh) * DH * SEQ;

  // staging sources: K chunks c=i*512+t (row=c>>4, q=c&15); V chunks (row=c>>3, q=c&7)
  const unsigned short* kp[2];
  const unsigned short* vp[2];
  #pragma unroll
  for (int i = 0; i < 2; ++i) {
    int c = i * 512 + t;
    int krow = c >> 4, kq = c & 15;
    kp[i] = kbase + (size_t)krow * NQKV + ((kq ^ (krow & 7)) << 3);
    int vrow = c >> 3, vq = c & 7;
    vp[i] = vtb + (size_t)vrow * SEQ + ((vq ^ (vrow & 7)) << 3);
  }

  const int qw0 = q0 + w * 16;

  // Q fragments hoisted: lane holds Q[row=qw0+rl][k=kg*8+j], 4 k-steps
  short8 qF[4];
  {
    const size_t qr = (size_t)(qw0 + rl) * NQKV + h * DH;
    #pragma unroll
    for (int ks = 0; ks < 4; ++ks)
      qF[ks] = *(const short8*)(qbase + qr + ks * 32 + kg * 8);
  }

  f32x4 Oc[8] = {};
  float mr = -3e38f, lr = 0.f;                  // per-lane state for q = qw0 + rl

  char* pwB = (char*)Pw[w] + rl * 128;          // this lane's P row base (bytes)
  const int pkey = (rl & 7) << 4;               // XOR key, bits 4-6
  const int nt = q0 / KB + 2;                   // kv tiles up to (incl.) diagonal

  // prologue: stage tile 0 into buffer 0 (4 GLL16 / wave)
  #pragma unroll
  for (int i = 0; i < 2; ++i) {
    GLL16(kp[i], (char*)Ks[0] + w * 1024 + i * 8192);
    GLL16(vp[i], (char*)Vs[0] + w * 1024 + i * 8192);
  }

  int cur = 0;
  for (int tt = 0; tt < nt; ++tt) {
    const int kv0 = tt * KB;
    const bool more = (tt + 1 < nt);
    if (more) {                                  // issue next-tile loads into buf^1
      #pragma unroll
      for (int i = 0; i < 2; ++i) {
        GLL16(kp[i] + (size_t)(kv0 + KB) * NQKV, (char*)Ks[cur ^ 1] + w * 1024 + i * 8192);
        GLL16(vp[i] + (kv0 + KB),               (char*)Vs[cur ^ 1] + w * 1024 + i * 8192);
      }
      asm volatile("s_waitcnt vmcnt(4)" ::: "memory");   // tile tt's 4 loads landed
    } else {
      asm volatile("s_waitcnt vmcnt(0)" ::: "memory");
    }
    __builtin_amdgcn_sched_barrier(0);
    __builtin_amdgcn_s_barrier();                // all waves' tile-tt loads visible

    if (kv0 < qw0 + 16) {                        // not fully masked (wave-uniform)
      const unsigned short* KsC = Ks[cur];
      const unsigned short* VsC = Vs[cur];

      // S^T = K Q : lane (rl,kg) holds S[q=qw0+rl][kv = kv0 + n*16 + kg*4 + r]
      f32x4 St[4] = {};
      __builtin_amdgcn_s_setprio(1);
      #pragma unroll
      for (int n = 0; n < 4; ++n) {
        const int kr = n * 16 + rl;
        #pragma unroll
        for (int ks = 0; ks < 4; ++ks) {
          short8 kF = *(const short8*)&KsC[kr * DH + (((ks * 4 + kg) ^ (kr & 7)) << 3)];
          St[n] = __builtin_amdgcn_mfma_f32_16x16x32_bf16(kF, qF[ks], St[n], 0, 0, 0);
        }
      }
      __builtin_amdgcn_s_setprio(0);

      // lane-local mask + max for q-row qw0+rl
      float mx = -3e38f;
      const bool diag = (kv0 + KB - 1) > qw0;    // tile straddles the diagonal
      if (diag) {
        const int thr = qw0 + rl - kv0;          // mask if kv-idx > thr
        #pragma unroll
        for (int n = 0; n < 4; ++n)
          #pragma unroll
          for (int r = 0; r < 4; ++r) {
            float s = St[n][r];
            if (n * 16 + kg * 4 + r > thr) s = -3e38f;
            St[n][r] = s;
            mx = fmaxf(mx, s);
          }
      } else {
        #pragma unroll
        for (int n = 0; n < 4; ++n)
          #pragma unroll
          for (int r = 0; r < 4; ++r) mx = fmaxf(mx, St[n][r]);
      }
      mx = fmaxf(mx, __shfl_xor(mx, 16));
      mx = fmaxf(mx, __shfl_xor(mx, 32));

      // deferred rescale (T13)
      if (__any(mx > mr + THR)) {
        const float mnew = fmaxf(mr, mx);
        const float sf = exp2f(mr - mnew);
        mr = mnew;
        lr *= sf;
        float sfv[4];
        #pragma unroll
        for (int r = 0; r < 4; ++r) sfv[r] = __shfl(sf, kg * 4 + r, 16);
        #pragma unroll
        for (int c = 0; c < 8; ++c)
          #pragma unroll
          for (int r = 0; r < 4; ++r) Oc[c][r] *= sfv[r];
      }

      // exp2 + pack (cvt_pk) + lane-local sum; P[q=rl][kv] -> LDS (XOR-swizzled)
      float rs = 0.f;
      #pragma unroll
      for (int n = 0; n < 4; ++n) {
        float e0 = exp2f(St[n][0] - mr);
        float e1 = exp2f(St[n][1] - mr);
        float e2 = exp2f(St[n][2] - mr);
        float e3 = exp2f(St[n][3] - mr);
        rs += (e0 + e1) + (e2 + e3);
        uint2 d;
        d.x = cvtpk_bf16(e0, e1);
        d.y = cvtpk_bf16(e2, e3);
        *(uint2*)(pwB + ((n * 32 + kg * 8) ^ pkey)) = d;
      }
      rs += __shfl_xor(rs, 16);
      rs += __shfl_xor(rs, 32);
      lr += rs;

      // PV: A = P[16][64] (row=rl, k=kv), B = V (col=d, k=kv) from Vs rows
      short8 pF[2];
      #pragma unroll
      for (int ks2 = 0; ks2 < 2; ++ks2)
        pF[ks2] = *(const short8*)(pwB + ((ks2 * 64 + kg * 16) ^ pkey));
      __builtin_amdgcn_s_setprio(1);
      #pragma unroll
      for (int c = 0; c < 8; ++c) {
        const int vr = c * 16 + rl;
        #pragma unroll
        for (int ks2 = 0; ks2 < 2; ++ks2) {
          short8 vF = *(const short8*)&VsC[vr * KB + (((ks2 * 4 + kg) ^ (vr & 7)) << 3)];
          Oc[c] = __builtin_amdgcn_mfma_f32_16x16x32_bf16(pF[ks2], vF, Oc[c], 0, 0, 0);
        }
      }
      __builtin_amdgcn_s_setprio(0);
    }

    __builtin_amdgcn_s_barrier();                // all waves done reading buf[cur]
    cur ^= 1;
  }

  // epilogue: O /= l (broadcast per output row), write bf16 [b*S+s][h*128+d]
  const float linv = 1.0f / lr;
  float inv[4];
  #pragma unroll
  for (int r = 0; r < 4; ++r) inv[r] = __shfl(linv, kg * 4 + r, 16);
  #pragma unroll
  for (int c = 0; c < 8; ++c)
    #pragma unroll
    for (int r = 0; r < 4; ++r) {
      int row = b * SEQ + qw0 + kg * 4 + r;
      obuf[(size_t)row * DMODEL + h * DH + c * 16 + rl] = f2bf(Oc[c][r] * inv[r]);
    }
}

// ---------------- launch ----------------------------------------------------

extern "C" void kernel_launch(void* const* d_in, const int* in_sizes, int n_in,
                              void* d_out, int out_size, void* d_ws, size_t ws_size,
                              hipStream_t stream) {
  const float* x  = (const float*)d_in[0];
  const float* wq = (const float*)d_in[1];
  const float* wk = (const float*)d_in[2];
  const float* wv = (const float*)d_in[3];
  const float* wo = (const float*)d_in[4];
  float* out = (float*)d_out;

  unsigned short* xb  = (unsigned short*)d_ws;                 // 4096x2048
  unsigned short* wT  = xb  + (size_t)MROWS * DMODEL;          // 3072x2048 (q|k|v transposed)
  unsigned short* woT = wT  + (size_t)NQKV * DMODEL;           // 2048x2048
  unsigned short* qkv = woT + (size_t)DMODEL * DMODEL;         // 4096x3072
  unsigned short* ob  = qkv + (size_t)MROWS * NQKV;            // 4096x2048
  float* tc = (float*)(ob + (size_t)MROWS * DMODEL);           // 2048x64
  float* ts = tc + SEQ * 64;
  // vt reuses the wT region (wT dead after the QKV GEMM)
  unsigned short* vtG = wT;

  k_prep<<<dim3(MROWS * DMODEL / 4 / 256), dim3(256), 0, stream>>>(x, xb, tc, ts);
  k_wtrans4<<<dim3(64, 64, 4), dim3(32, 8), 0, stream>>>(wq, wk, wv, wo, wT, woT);

  // QKV: 4096x3072 = (16 x 16) tiles of 256x192 -> exactly 1 block/CU, no tail
  k_gemm256<192, false, true><<<dim3(NQKV / 192, MROWS / 256), dim3(512), 0, stream>>>(
      xb, wT, qkv, MROWS, NQKV, DMODEL, tc, ts);
  k_vtrans<<<dim3(SEQ / 32, DH / 32, BATCH * NKVH), dim3(32, 8), 0, stream>>>(qkv, vtG);
  k_attn<<<dim3(512), dim3(512), 0, stream>>>(qkv, vtG, ob);
  k_gemm256<128, true, false><<<dim3(DMODEL / 128, MROWS / 256), dim3(512), 0, stream>>>(
      ob, woT, out, MROWS, DMODEL, DMODEL, nullptr, nullptr);
}

// Round 16
// 211.655 us; speedup vs baseline: 1.2952x; 1.0037x over previous
//
#include <hip/hip_runtime.h>
#include <cstdint>
#include <cstddef>

using short8 = __attribute__((ext_vector_type(8))) short;
using f32x4  = __attribute__((ext_vector_type(4))) float;
using u16x4  = __attribute__((ext_vector_type(4))) unsigned short;

#define DEV __device__ __forceinline__

DEV unsigned short f2bf(float f) {
  unsigned int u = __builtin_bit_cast(unsigned int, f);
  u += 0x7fffu + ((u >> 16) & 1u);          // RNE
  return (unsigned short)(u >> 16);
}
DEV float bf2f(unsigned short h) {
  unsigned int u = ((unsigned int)h) << 16;
  return __builtin_bit_cast(float, u);
}
DEV unsigned int cvtpk_bf16(float lo, float hi) {  // d.lo16=bf16(lo), d.hi16=bf16(hi)
  unsigned int d;
  asm("v_cvt_pk_bf16_f32 %0, %1, %2" : "=v"(d) : "v"(lo), "v"(hi));
  return d;
}

// direct global->LDS, width 16B (m97 lever). LDS dest = wave-uniform base + lane*16.
#define GLL16(gp, lp)                                                          \
  __builtin_amdgcn_global_load_lds(                                            \
      (const __attribute__((address_space(1))) char*)(const char*)(gp),        \
      (__attribute__((address_space(3))) char*)(char*)(lp), 16, 0, 0)

constexpr int BATCH = 2, SEQ = 2048, DMODEL = 2048, NH = 16, NKVH = 4, DH = 128;
constexpr int MROWS = BATCH * SEQ;            // 4096
constexpr int NQKV  = DMODEL + 2 * NKVH * DH; // 3072 (Q | K | V)
constexpr int KOFF  = DMODEL;                 // 2048
constexpr int VOFF  = DMODEL + NKVH * DH;     // 2560
constexpr float SM_L2 = 0.12751388158f;       // (1/sqrt(128)) * log2(e), folded into Q

// ---------------- prep kernels ----------------

// fused: x fp32 -> bf16 cast (all blocks) + RoPE cos/sin tables (first 512 blocks)
__global__ void k_prep(const float* __restrict__ x, unsigned short* __restrict__ xb,
                       float* __restrict__ tc, float* __restrict__ ts) {
  int id = blockIdx.x * 256 + threadIdx.x;    // MROWS*DMODEL/4 total
  if (id < SEQ * 64) {
    int pos = id >> 6, i = id & 63;
    float freq = __expf(-(float)i * 0.14391157f);
    float ang = (float)pos * freq;
    tc[id] = cosf(ang);
    ts[id] = sinf(ang);
  }
  float4 v = ((const float4*)x)[id];
  u16x4 o = { f2bf(v.x), f2bf(v.y), f2bf(v.z), f2bf(v.w) };
  ((u16x4*)xb)[id] = o;
}

// all 4 weight transposes in one launch: z=0 wq->wT, z=1 wo->woT, z=2 wk, z=3 wv
__global__ __launch_bounds__(256) void k_wtrans4(
    const float* __restrict__ wq, const float* __restrict__ wk,
    const float* __restrict__ wv, const float* __restrict__ wo,
    unsigned short* __restrict__ wT, unsigned short* __restrict__ woT) {
  __shared__ float tile[32][33];
  const int z = blockIdx.z;
  const float* src; unsigned short* dst; int N;
  if (z == 0)      { src = wq; dst = wT;                        N = 2048; }
  else if (z == 1) { src = wo; dst = woT;                       N = 2048; }
  else if (z == 2) { src = wk; dst = wT + (size_t)KOFF * 2048;  N = 512; }
  else             { src = wv; dst = wT + (size_t)VOFF * 2048;  N = 512; }
  int n0 = blockIdx.x * 32, k0 = blockIdx.y * 32;
  if (n0 >= N) return;
  int tx = threadIdx.x, ty = threadIdx.y;     // 32 x 8
  #pragma unroll
  for (int r = ty; r < 32; r += 8)
    tile[r][tx] = src[(size_t)(k0 + r) * N + n0 + tx];
  __syncthreads();
  #pragma unroll
  for (int r = ty; r < 32; r += 8)
    dst[(size_t)(n0 + r) * 2048 + k0 + tx] = f2bf(tile[tx][r]);
}

// V region of qkv -> vt[b][kvh][d=128][s=2048]  (bf16 -> bf16 transpose)
__global__ __launch_bounds__(256) void k_vtrans(const unsigned short* __restrict__ qkv,
                                                unsigned short* __restrict__ vt) {
  __shared__ unsigned short tile[32][33];
  int s0 = blockIdx.x * 32, d0 = blockIdx.y * 32;
  int bk = blockIdx.z;                         // b*4 + kvh
  const unsigned short* src = qkv + (size_t)(bk >> 2) * SEQ * NQKV + VOFF + (bk & 3) * DH;
  unsigned short* dst = vt + ((size_t)bk * DH + d0) * SEQ + s0;
  int tx = threadIdx.x, ty = threadIdx.y;      // 32 x 8
  #pragma unroll
  for (int r = ty; r < 32; r += 8)
    tile[r][tx] = src[(size_t)(s0 + r) * NQKV + d0 + tx];
  __syncthreads();
  #pragma unroll
  for (int r = ty; r < 32; r += 8)
    dst[(size_t)r * SEQ + tx] = tile[tx][r];
}

// ---------------- big-tile GEMM: C[m][n] = sum_k A[m][k]*Bt[n][k] ------------
// 256xBNT tile (BNT in {128,192,256}), BK=64, 512 thr / 8 waves (2M x 4N),
// double-buffered LDS, counted vmcnt (T3/T4), ^(row&7) chunk swizzle (T2),
// setprio around MFMA clusters (T5). LDS addresses hoisted: per-lane XOR key
// is loop-invariant (all row terms except rl are ==0 mod 8), so reads are
// (invariant base) + (cur toggle) + (compile-time immediate).

template <int BNT, bool OUTF32, bool ROPE>
__global__ __launch_bounds__(512, 2) void k_gemm256(
    const unsigned short* __restrict__ A,   // M x K bf16
    const unsigned short* __restrict__ Bt,  // N x K bf16
    void* __restrict__ C, int M, int N, int K,
    const float* __restrict__ tc, const float* __restrict__ ts) {
  constexpr int NF = BNT / 64;              // n-frags per wave (per-wave N = BNT/4)
  __shared__ unsigned short As[2][256 * 64];
  __shared__ unsigned short Bs[2][BNT * 64];

  const int t = threadIdx.x, l = t & 63, w = t >> 6;
  const int rl = l & 15, kg = l >> 4;
  const int wm = w >> 2, wn = w & 3;

  // XCD-aware swizzle (T1): nwg % 8 == 0 for all instantiations
  const int gx = gridDim.x;
  const int nwg = gx * gridDim.y;
  const int idl = blockIdx.y * gx + blockIdx.x;
  const int swz = (idl & 7) * (nwg >> 3) + (idl >> 3);
  const int m0 = (swz / gx) * 256, n0 = (swz % gx) * BNT;

  // staging sources (pre-swizzled: LDS dest linear, source permuted, read XOR'd)
  const unsigned short* aSrc[4];
  const unsigned short* bSrc[NF];
  #pragma unroll
  for (int i = 0; i < 4; ++i) {
    int c = i * 512 + t, row = c >> 3, q = c & 7;
    aSrc[i] = A + (size_t)(m0 + row) * K + ((q ^ (row & 7)) << 3);
  }
  #pragma unroll
  for (int i = 0; i < NF; ++i) {
    int c = i * 512 + t, row = c >> 3, q = c & 7;
    bSrc[i] = Bt + (size_t)(n0 + row) * K + ((q ^ (row & 7)) << 3);
  }

  // hoisted LDS read offsets (bytes): row&7 == rl&7 for all fragment rows
  const int pkey = (rl & 7) << 4;
  int oA[2], oB[2];
  #pragma unroll
  for (int ks = 0; ks < 2; ++ks) {
    oA[ks] = (wm * 128 + rl) * 128 + (((ks * 4 + kg) << 4) ^ pkey);
    oB[ks] = (wn * (BNT / 4) + rl) * 128 + (((ks * 4 + kg) << 4) ^ pkey);
  }
  const char* AsB = (const char*)As;
  const char* BsB = (const char*)Bs;

  f32x4 acc[8][NF] = {};

  const int nk = K / 64;
  // prologue: stage K-tile 0 into buffer 0
  #pragma unroll
  for (int i = 0; i < 4; ++i) GLL16(aSrc[i], (char*)As[0] + i * 8192 + t * 16);
  #pragma unroll
  for (int i = 0; i < NF; ++i) GLL16(bSrc[i], (char*)Bs[0] + i * 8192 + t * 16);

  int cur = 0;
  for (int kt = 0; kt < nk; ++kt) {
    if (kt + 1 < nk) {                           // issue next K-tile into buf^1
      const int off = (kt + 1) * 64;
      #pragma unroll
      for (int i = 0; i < 4; ++i)
        GLL16(aSrc[i] + off, (char*)As[cur ^ 1] + i * 8192 + t * 16);
      #pragma unroll
      for (int i = 0; i < NF; ++i)
        GLL16(bSrc[i] + off, (char*)Bs[cur ^ 1] + i * 8192 + t * 16);
      if constexpr (NF == 4)      asm volatile("s_waitcnt vmcnt(8)" ::: "memory");
      else if constexpr (NF == 3) asm volatile("s_waitcnt vmcnt(7)" ::: "memory");
      else                        asm volatile("s_waitcnt vmcnt(6)" ::: "memory");
    } else {
      asm volatile("s_waitcnt vmcnt(0)" ::: "memory");
    }
    __builtin_amdgcn_sched_barrier(0);
    __builtin_amdgcn_s_barrier();                // K-tile kt resident in buf[cur]

    const int coA = cur ? 32768 : 0;             // As per-buffer bytes
    const int coB = cur ? BNT * 128 : 0;         // Bs per-buffer bytes
    int cA[2] = { oA[0] + coA, oA[1] + coA };
    int cB[2] = { oB[0] + coB, oB[1] + coB };

    short8 aF[4][2], bF[NF][2];
    // A-half0 phases: per n-frag j, read bF[j] then 8 MFMA
    #pragma unroll
    for (int mi = 0; mi < 4; ++mi)
      #pragma unroll
      for (int ks = 0; ks < 2; ++ks)
        aF[mi][ks] = *(const short8*)(AsB + cA[ks] + mi * 2048);
    #pragma unroll
    for (int j = 0; j < NF; ++j) {
      #pragma unroll
      for (int ks = 0; ks < 2; ++ks)
        bF[j][ks] = *(const short8*)(BsB + cB[ks] + j * 2048);
      __builtin_amdgcn_s_setprio(1);
      #pragma unroll
      for (int mi = 0; mi < 4; ++mi)
        #pragma unroll
        for (int ks = 0; ks < 2; ++ks)
          acc[mi][j] = __builtin_amdgcn_mfma_f32_16x16x32_bf16(aF[mi][ks], bF[j][ks], acc[mi][j], 0, 0, 0);
      __builtin_amdgcn_s_setprio(0);
    }
    // A-half1 phases (bF already live)
    #pragma unroll
    for (int mi = 0; mi < 4; ++mi)
      #pragma unroll
      for (int ks = 0; ks < 2; ++ks)
        aF[mi][ks] = *(const short8*)(AsB + cA[ks] + (4 + mi) * 2048);
    #pragma unroll
    for (int j = 0; j < NF; ++j) {
      __builtin_amdgcn_s_setprio(1);
      #pragma unroll
      for (int mi = 0; mi < 4; ++mi)
        #pragma unroll
        for (int ks = 0; ks < 2; ++ks)
          acc[4 + mi][j] = __builtin_amdgcn_mfma_f32_16x16x32_bf16(aF[mi][ks], bF[j][ks], acc[4 + mi][j], 0, 0, 0);
      __builtin_amdgcn_s_setprio(0);
    }

    __builtin_amdgcn_s_barrier();                // all waves done reading buf[cur]
    cur ^= 1;
  }

  // epilogue; C/D layout (m89-verified): col = lane&15, row = (lane>>4)*4 + reg
  #pragma unroll
  for (int mf = 0; mf < 8; ++mf) {
    #pragma unroll
    for (int nf = 0; nf < NF; ++nf) {
      const int row0 = m0 + wm * 128 + mf * 16 + kg * 4;
      const int colb = n0 + wn * (BNT / 4) + nf * 16;
      const int col = colb + rl;
      if constexpr (ROPE) {
        if (colb < VOFF) {                       // Q or K region (V untouched)
          const int dd = (col & 127) >> 1;       // pair index within head
          const float sgn = (col & 1) ? 1.0f : -1.0f;
          const float qs = (colb < KOFF) ? SM_L2 : 1.0f;
          #pragma unroll
          for (int r = 0; r < 4; ++r) {
            const int s = (row0 + r) & (SEQ - 1);
            const float c = tc[s * 64 + dd], sn = ts[s * 64 + dd];
            const float xv = acc[mf][nf][r];
            const float xp = __shfl_xor(xv, 1);  // partner column (col^1)
            acc[mf][nf][r] = (xv * c + sgn * xp * sn) * qs;
          }
        }
      }
      #pragma unroll
      for (int r = 0; r < 4; ++r) {
        if constexpr (OUTF32)
          ((float*)C)[(size_t)(row0 + r) * N + col] = acc[mf][nf][r];
        else
          ((unsigned short*)C)[(size_t)(row0 + r) * N + col] = f2bf(acc[mf][nf][r]);
      }
    }
  }
}

// ---------------- flash attention, causal, GQA ------------------------------
// 8 waves x 16 q-rows (QB=128), KVBLK=64 DOUBLE-BUFFERED via GLL16 with counted
// vmcnt(4) + raw barriers (T3/T4); swapped QK^T -> lane-local softmax; P in LDS
// (XOR-swizzled, stride 64). LDS read/write offsets hoisted out of the kv loop:
// kr&7 == vr&7 == rl&7 (loop-invariant), P offsets fully invariant.

constexpr int QB = 128, KB = 64;
constexpr float THR = 8.0f;                    // defer-max threshold (log2 domain)

__global__ __launch_bounds__(512, 4) void k_attn(const unsigned short* __restrict__ qkv,
                                                 const unsigned short* __restrict__ vt,
                                                 unsigned short* __restrict__ obuf) {
  __shared__ unsigned short Ks[2][KB * DH];     // 2 x [64][128], chunk-XOR ^(row&7)
  __shared__ unsigned short Vs[2][DH * KB];     // 2 x [128][64], chunk-XOR ^(row&7)
  __shared__ unsigned short Pw[8][16 * 64];     // per-wave P, stride 64, XOR ^(rl&7)<<4

  const int t = threadIdx.x, l = t & 63, w = t >> 6;
  const int rl = l & 15, kg = l >> 4;

  // complementary-pair decode: ids i and i+256 get q-tiles qt and 15-qt
  const int id = blockIdx.x;                    // [0, 512)
  const int b = id >> 8;
  const int u = id & 255;
  const int h = u >> 4;
  const int qtr = u & 15;
  const int qt = b ? (15 - qtr) : qtr;
  const int q0 = qt * QB;
  const int kvh = h >> 2;

  const unsigned short* qbase = qkv + (size_t)b * SEQ * NQKV;
  const unsigned short* kbase = qbase + KOFF + kvh * DH;
  const unsigned short* vtb = vt + (size_t)(b * NKVH + kvh) * DH * SEQ;

  // staging sources: K chunks c=i*512+t (row=c>>4, q=c&15); V chunks (row=c>>3, q=c&7)
  const unsigned short* kp[2];
  const unsigned short* vp[2];
  #pragma unroll
  for (int i = 0; i < 2; ++i) {
    int c = i * 512 + t;
    int krow = c >> 4, kq = c & 15;
    kp[i] = kbase + (size_t)krow * NQKV + ((kq ^ (krow & 7)) << 3);
    int vrow = c >> 3, vq = c & 7;
    vp[i] = vtb + (size_t)vrow * SEQ + ((vq ^ (vrow & 7)) << 3);
  }

  const int qw0 = q0 + w * 16;

  // Q fragments hoisted: lane holds Q[row=qw0+rl][k=kg*8+j], 4 k-steps
  short8 qF[4];
  {
    const size_t qr = (size_t)(qw0 + rl) * NQKV + h * DH;
    #pragma unroll
    for (int ks = 0; ks < 4; ++ks)
      qF[ks] = *(const short8*)(qbase + qr + ks * 32 + kg * 8);
  }

  // hoisted LDS byte offsets (loop-invariant): kF = oK[ks] + co + n*4096,
  // vF = oV[ks2] + co + c*2048; P offsets fully invariant (not dbuf'd).
  const int pkey = (rl & 7) << 4;
  int oK[4], oV[2], oPW[4], oPR[2];
  #pragma unroll
  for (int ks = 0; ks < 4; ++ks) oK[ks] = rl * 256 + (((ks * 4 + kg) << 4) ^ pkey);
  #pragma unroll
  for (int ks = 0; ks < 2; ++ks) oV[ks] = rl * 128 + (((ks * 4 + kg) << 4) ^ pkey);
  const int pwb = w * 2048 + rl * 128;
  #pragma unroll
  for (int n = 0; n < 4; ++n) oPW[n] = pwb + ((n * 32 + kg * 8) ^ pkey);
  #pragma unroll
  for (int ks = 0; ks < 2; ++ks) oPR[ks] = pwb + ((ks * 64 + kg * 16) ^ pkey);
  const char* KsB = (const char*)Ks;
  const char* VsB = (const char*)Vs;
  char* PwB = (char*)Pw;

  f32x4 Oc[8] = {};
  float mr = -3e38f, lr = 0.f;                  // per-lane state for q = qw0 + rl

  const int nt = q0 / KB + 2;                   // kv tiles up to (incl.) diagonal

  // prologue: stage tile 0 into buffer 0 (4 GLL16 / wave)
  #pragma unroll
  for (int i = 0; i < 2; ++i) {
    GLL16(kp[i], (char*)Ks[0] + w * 1024 + i * 8192);
    GLL16(vp[i], (char*)Vs[0] + w * 1024 + i * 8192);
  }

  int cur = 0;
  for (int tt = 0; tt < nt; ++tt) {
    const int kv0 = tt * KB;
    const bool more = (tt + 1 < nt);
    if (more) {                                  // issue next-tile loads into buf^1
      #pragma unroll
      for (int i = 0; i < 2; ++i) {
        GLL16(kp[i] + (size_t)(kv0 + KB) * NQKV, (char*)Ks[cur ^ 1] + w * 1024 + i * 8192);
        GLL16(vp[i] + (kv0 + KB),               (char*)Vs[cur ^ 1] + w * 1024 + i * 8192);
      }
      asm volatile("s_waitcnt vmcnt(4)" ::: "memory");   // tile tt's 4 loads landed
    } else {
      asm volatile("s_waitcnt vmcnt(0)" ::: "memory");
    }
    __builtin_amdgcn_sched_barrier(0);
    __builtin_amdgcn_s_barrier();                // all waves' tile-tt loads visible

    if (kv0 < qw0 + 16) {                        // not fully masked (wave-uniform)
      const int co = cur << 14;                  // cur * 16384 (per-buffer bytes)
      int cK[4] = { oK[0] + co, oK[1] + co, oK[2] + co, oK[3] + co };
      int cV[2] = { oV[0] + co, oV[1] + co };

      // S^T = K Q : lane (rl,kg) holds S[q=qw0+rl][kv = kv0 + n*16 + kg*4 + r]
      f32x4 St[4] = {};
      __builtin_amdgcn_s_setprio(1);
      #pragma unroll
      for (int n = 0; n < 4; ++n) {
        #pragma unroll
        for (int ks = 0; ks < 4; ++ks) {
          short8 kF = *(const short8*)(KsB + cK[ks] + n * 4096);
          St[n] = __builtin_amdgcn_mfma_f32_16x16x32_bf16(kF, qF[ks], St[n], 0, 0, 0);
        }
      }
      __builtin_amdgcn_s_setprio(0);

      // lane-local mask + max for q-row qw0+rl
      float mx = -3e38f;
      const bool diag = (kv0 + KB - 1) > qw0;    // tile straddles the diagonal
      if (diag) {
        const int thr = qw0 + rl - kv0;          // mask if kv-idx > thr
        #pragma unroll
        for (int n = 0; n < 4; ++n)
          #pragma unroll
          for (int r = 0; r < 4; ++r) {
            float s = St[n][r];
            if (n * 16 + kg * 4 + r > thr) s = -3e38f;
            St[n][r] = s;
            mx = fmaxf(mx, s);
          }
      } else {
        #pragma unroll
        for (int n = 0; n < 4; ++n)
          #pragma unroll
          for (int r = 0; r < 4; ++r) mx = fmaxf(mx, St[n][r]);
      }
      mx = fmaxf(mx, __shfl_xor(mx, 16));
      mx = fmaxf(mx, __shfl_xor(mx, 32));

      // deferred rescale (T13)
      if (__any(mx > mr + THR)) {
        const float mnew = fmaxf(mr, mx);
        const float sf = exp2f(mr - mnew);
        mr = mnew;
        lr *= sf;
        float sfv[4];
        #pragma unroll
        for (int r = 0; r < 4; ++r) sfv[r] = __shfl(sf, kg * 4 + r, 16);
        #pragma unroll
        for (int c = 0; c < 8; ++c)
          #pragma unroll
          for (int r = 0; r < 4; ++r) Oc[c][r] *= sfv[r];
      }

      // exp2 + pack (cvt_pk) + lane-local sum; P[q=rl][kv] -> LDS (XOR-swizzled)
      float rs = 0.f;
      #pragma unroll
      for (int n = 0; n < 4; ++n) {
        float e0 = exp2f(St[n][0] - mr);
        float e1 = exp2f(St[n][1] - mr);
        float e2 = exp2f(St[n][2] - mr);
        float e3 = exp2f(St[n][3] - mr);
        rs += (e0 + e1) + (e2 + e3);
        uint2 d;
        d.x = cvtpk_bf16(e0, e1);
        d.y = cvtpk_bf16(e2, e3);
        *(uint2*)(PwB + oPW[n]) = d;
      }
      rs += __shfl_xor(rs, 16);
      rs += __shfl_xor(rs, 32);
      lr += rs;

      // PV: A = P[16][64] (row=rl, k=kv), B = V (col=d, k=kv) from Vs rows
      short8 pF[2];
      #pragma unroll
      for (int ks2 = 0; ks2 < 2; ++ks2)
        pF[ks2] = *(const short8*)(PwB + oPR[ks2]);
      __builtin_amdgcn_s_setprio(1);
      #pragma unroll
      for (int c = 0; c < 8; ++c) {
        #pragma unroll
        for (int ks2 = 0; ks2 < 2; ++ks2) {
          short8 vF = *(const short8*)(VsB + cV[ks2] + c * 2048);
          Oc[c] = __builtin_amdgcn_mfma_f32_16x16x32_bf16(pF[ks2], vF, Oc[c], 0, 0, 0);
        }
      }
      __builtin_amdgcn_s_setprio(0);
    }

    __builtin_amdgcn_s_barrier();                // all waves done reading buf[cur]
    cur ^= 1;
  }

  // epilogue: O /= l (broadcast per output row), write bf16 [b*S+s][h*128+d]
  const float linv = 1.0f / lr;
  float inv[4];
  #pragma unroll
  for (int r = 0; r < 4; ++r) inv[r] = __shfl(linv, kg * 4 + r, 16);
  #pragma unroll
  for (int c = 0; c < 8; ++c)
    #pragma unroll
    for (int r = 0; r < 4; ++r) {
      int row = b * SEQ + qw0 + kg * 4 + r;
      obuf[(size_t)row * DMODEL + h * DH + c * 16 + rl] = f2bf(Oc[c][r] * inv[r]);
    }
}

// ---------------- launch ----------------------------------------------------

extern "C" void kernel_launch(void* const* d_in, const int* in_sizes, int n_in,
                              void* d_out, int out_size, void* d_ws, size_t ws_size,
                              hipStream_t stream) {
  const float* x  = (const float*)d_in[0];
  const float* wq = (const float*)d_in[1];
  const float* wk = (const float*)d_in[2];
  const float* wv = (const float*)d_in[3];
  const float* wo = (const float*)d_in[4];
  float* out = (float*)d_out;

  unsigned short* xb  = (unsigned short*)d_ws;                 // 4096x2048
  unsigned short* wT  = xb  + (size_t)MROWS * DMODEL;          // 3072x2048 (q|k|v transposed)
  unsigned short* woT = wT  + (size_t)NQKV * DMODEL;           // 2048x2048
  unsigned short* qkv = woT + (size_t)DMODEL * DMODEL;         // 4096x3072
  unsigned short* ob  = qkv + (size_t)MROWS * NQKV;            // 4096x2048
  float* tc = (float*)(ob + (size_t)MROWS * DMODEL);           // 2048x64
  float* ts = tc + SEQ * 64;
  // vt reuses the wT region (wT dead after the QKV GEMM)
  unsigned short* vtG = wT;

  k_prep<<<dim3(MROWS * DMODEL / 4 / 256), dim3(256), 0, stream>>>(x, xb, tc, ts);
  k_wtrans4<<<dim3(64, 64, 4), dim3(32, 8), 0, stream>>>(wq, wk, wv, wo, wT, woT);

  // QKV: 4096x3072 = (16 x 16) tiles of 256x192 -> exactly 1 block/CU, no tail
  k_gemm256<192, false, true><<<dim3(NQKV / 192, MROWS / 256), dim3(512), 0, stream>>>(
      xb, wT, qkv, MROWS, NQKV, DMODEL, tc, ts);
  k_vtrans<<<dim3(SEQ / 32, DH / 32, BATCH * NKVH), dim3(32, 8), 0, stream>>>(qkv, vtG);
  k_attn<<<dim3(512), dim3(512), 0, stream>>>(qkv, vtG, ob);
  k_gemm256<128, true, false><<<dim3(DMODEL / 128, MROWS / 256), dim3(512), 0, stream>>>(
      ob, woT, out, MROWS, DMODEL, DMODEL, nullptr, nullptr);
}

// Round 17
// 209.249 us; speedup vs baseline: 1.3101x; 1.0115x over previous
//
#include <hip/hip_runtime.h>
#include <cstdint>
#include <cstddef>

using short8 = __attribute__((ext_vector_type(8))) short;
using f32x4  = __attribute__((ext_vector_type(4))) float;
using u16x4  = __attribute__((ext_vector_type(4))) unsigned short;

#define DEV __device__ __forceinline__

DEV unsigned short f2bf(float f) {
  unsigned int u = __builtin_bit_cast(unsigned int, f);
  u += 0x7fffu + ((u >> 16) & 1u);          // RNE
  return (unsigned short)(u >> 16);
}
DEV float bf2f(unsigned short h) {
  unsigned int u = ((unsigned int)h) << 16;
  return __builtin_bit_cast(float, u);
}
DEV unsigned int cvtpk_bf16(float lo, float hi) {  // d.lo16=bf16(lo), d.hi16=bf16(hi)
  unsigned int d;
  asm("v_cvt_pk_bf16_f32 %0, %1, %2" : "=v"(d) : "v"(lo), "v"(hi));
  return d;
}

// direct global->LDS, width 16B (m97 lever). LDS dest = wave-uniform base + lane*16.
#define GLL16(gp, lp)                                                          \
  __builtin_amdgcn_global_load_lds(                                            \
      (const __attribute__((address_space(1))) char*)(const char*)(gp),        \
      (__attribute__((address_space(3))) char*)(char*)(lp), 16, 0, 0)

constexpr int BATCH = 2, SEQ = 2048, DMODEL = 2048, NH = 16, NKVH = 4, DH = 128;
constexpr int MROWS = BATCH * SEQ;            // 4096
constexpr int NQKV  = DMODEL + 2 * NKVH * DH; // 3072 (Q | K | V)
constexpr int KOFF  = DMODEL;                 // 2048
constexpr int VOFF  = DMODEL + NKVH * DH;     // 2560
constexpr float SM_L2 = 0.12751388158f;       // (1/sqrt(128)) * log2(e), folded into Q

// ---------------- prep kernels ----------------

// fused: x fp32 -> bf16 cast (all blocks) + RoPE cos/sin tables (first 512 blocks)
__global__ void k_prep(const float* __restrict__ x, unsigned short* __restrict__ xb,
                       float* __restrict__ tc, float* __restrict__ ts) {
  int id = blockIdx.x * 256 + threadIdx.x;    // MROWS*DMODEL/4 total
  if (id < SEQ * 64) {
    int pos = id >> 6, i = id & 63;
    float freq = __expf(-(float)i * 0.14391157f);
    float ang = (float)pos * freq;
    tc[id] = cosf(ang);
    ts[id] = sinf(ang);
  }
  float4 v = ((const float4*)x)[id];
  u16x4 o = { f2bf(v.x), f2bf(v.y), f2bf(v.z), f2bf(v.w) };
  ((u16x4*)xb)[id] = o;
}

// all 4 weight transposes in one launch: z=0 wq->wT, z=1 wo->woT, z=2 wk, z=3 wv
__global__ __launch_bounds__(256) void k_wtrans4(
    const float* __restrict__ wq, const float* __restrict__ wk,
    const float* __restrict__ wv, const float* __restrict__ wo,
    unsigned short* __restrict__ wT, unsigned short* __restrict__ woT) {
  __shared__ float tile[32][33];
  const int z = blockIdx.z;
  const float* src; unsigned short* dst; int N;
  if (z == 0)      { src = wq; dst = wT;                        N = 2048; }
  else if (z == 1) { src = wo; dst = woT;                       N = 2048; }
  else if (z == 2) { src = wk; dst = wT + (size_t)KOFF * 2048;  N = 512; }
  else             { src = wv; dst = wT + (size_t)VOFF * 2048;  N = 512; }
  int n0 = blockIdx.x * 32, k0 = blockIdx.y * 32;
  if (n0 >= N) return;
  int tx = threadIdx.x, ty = threadIdx.y;     // 32 x 8
  #pragma unroll
  for (int r = ty; r < 32; r += 8)
    tile[r][tx] = src[(size_t)(k0 + r) * N + n0 + tx];
  __syncthreads();
  #pragma unroll
  for (int r = ty; r < 32; r += 8)
    dst[(size_t)(n0 + r) * 2048 + k0 + tx] = f2bf(tile[tx][r]);
}

// ---------------- big-tile GEMM: C[m][n] = sum_k A[m][k]*Bt[n][k] ------------
// 256xBNT tile (BNT in {128,192,256}), BK=64, 512 thr / 8 waves (2M x 4N),
// double-buffered LDS, counted vmcnt (T3/T4), ^(row&7) chunk swizzle (T2),
// setprio around MFMA clusters (T5). ROPE=true: rotary fused into epilogue for
// Q/K columns; V columns written TRANSPOSED to vtO ([b][kvh][d][s]) instead of
// C, eliminating the separate k_vtrans pass.

template <int BNT, bool OUTF32, bool ROPE>
__global__ __launch_bounds__(512, 2) void k_gemm256(
    const unsigned short* __restrict__ A,   // M x K bf16
    const unsigned short* __restrict__ Bt,  // N x K bf16
    void* __restrict__ C, int M, int N, int K,
    const float* __restrict__ tc, const float* __restrict__ ts,
    unsigned short* __restrict__ vtO) {
  constexpr int NF = BNT / 64;              // n-frags per wave (per-wave N = BNT/4)
  __shared__ unsigned short As[2][256 * 64];
  __shared__ unsigned short Bs[2][BNT * 64];

  const int t = threadIdx.x, l = t & 63, w = t >> 6;
  const int rl = l & 15, kg = l >> 4;
  const int wm = w >> 2, wn = w & 3;

  // XCD-aware swizzle (T1): nwg % 8 == 0 for all instantiations
  const int gx = gridDim.x;
  const int nwg = gx * gridDim.y;
  const int idl = blockIdx.y * gx + blockIdx.x;
  const int swz = (idl & 7) * (nwg >> 3) + (idl >> 3);
  const int m0 = (swz / gx) * 256, n0 = (swz % gx) * BNT;

  // staging sources (pre-swizzled: LDS dest linear, source permuted, read XOR'd)
  const unsigned short* aSrc[4];
  const unsigned short* bSrc[NF];
  #pragma unroll
  for (int i = 0; i < 4; ++i) {
    int c = i * 512 + t, row = c >> 3, q = c & 7;
    aSrc[i] = A + (size_t)(m0 + row) * K + ((q ^ (row & 7)) << 3);
  }
  #pragma unroll
  for (int i = 0; i < NF; ++i) {
    int c = i * 512 + t, row = c >> 3, q = c & 7;
    bSrc[i] = Bt + (size_t)(n0 + row) * K + ((q ^ (row & 7)) << 3);
  }

  // hoisted LDS read offsets (bytes): row&7 == rl&7 for all fragment rows
  const int pkey = (rl & 7) << 4;
  int oA[2], oB[2];
  #pragma unroll
  for (int ks = 0; ks < 2; ++ks) {
    oA[ks] = (wm * 128 + rl) * 128 + (((ks * 4 + kg) << 4) ^ pkey);
    oB[ks] = (wn * (BNT / 4) + rl) * 128 + (((ks * 4 + kg) << 4) ^ pkey);
  }
  const char* AsB = (const char*)As;
  const char* BsB = (const char*)Bs;

  f32x4 acc[8][NF] = {};

  const int nk = K / 64;
  // prologue: stage K-tile 0 into buffer 0
  #pragma unroll
  for (int i = 0; i < 4; ++i) GLL16(aSrc[i], (char*)As[0] + i * 8192 + t * 16);
  #pragma unroll
  for (int i = 0; i < NF; ++i) GLL16(bSrc[i], (char*)Bs[0] + i * 8192 + t * 16);

  int cur = 0;
  for (int kt = 0; kt < nk; ++kt) {
    if (kt + 1 < nk) {                           // issue next K-tile into buf^1
      const int off = (kt + 1) * 64;
      #pragma unroll
      for (int i = 0; i < 4; ++i)
        GLL16(aSrc[i] + off, (char*)As[cur ^ 1] + i * 8192 + t * 16);
      #pragma unroll
      for (int i = 0; i < NF; ++i)
        GLL16(bSrc[i] + off, (char*)Bs[cur ^ 1] + i * 8192 + t * 16);
      if constexpr (NF == 4)      asm volatile("s_waitcnt vmcnt(8)" ::: "memory");
      else if constexpr (NF == 3) asm volatile("s_waitcnt vmcnt(7)" ::: "memory");
      else                        asm volatile("s_waitcnt vmcnt(6)" ::: "memory");
    } else {
      asm volatile("s_waitcnt vmcnt(0)" ::: "memory");
    }
    __builtin_amdgcn_sched_barrier(0);
    __builtin_amdgcn_s_barrier();                // K-tile kt resident in buf[cur]

    const int coA = cur ? 32768 : 0;             // As per-buffer bytes
    const int coB = cur ? BNT * 128 : 0;         // Bs per-buffer bytes
    int cA[2] = { oA[0] + coA, oA[1] + coA };
    int cB[2] = { oB[0] + coB, oB[1] + coB };

    short8 aF[4][2], bF[NF][2];
    // A-half0 phases: per n-frag j, read bF[j] then 8 MFMA
    #pragma unroll
    for (int mi = 0; mi < 4; ++mi)
      #pragma unroll
      for (int ks = 0; ks < 2; ++ks)
        aF[mi][ks] = *(const short8*)(AsB + cA[ks] + mi * 2048);
    #pragma unroll
    for (int j = 0; j < NF; ++j) {
      #pragma unroll
      for (int ks = 0; ks < 2; ++ks)
        bF[j][ks] = *(const short8*)(BsB + cB[ks] + j * 2048);
      __builtin_amdgcn_s_setprio(1);
      #pragma unroll
      for (int mi = 0; mi < 4; ++mi)
        #pragma unroll
        for (int ks = 0; ks < 2; ++ks)
          acc[mi][j] = __builtin_amdgcn_mfma_f32_16x16x32_bf16(aF[mi][ks], bF[j][ks], acc[mi][j], 0, 0, 0);
      __builtin_amdgcn_s_setprio(0);
    }
    // A-half1 phases (bF already live)
    #pragma unroll
    for (int mi = 0; mi < 4; ++mi)
      #pragma unroll
      for (int ks = 0; ks < 2; ++ks)
        aF[mi][ks] = *(const short8*)(AsB + cA[ks] + (4 + mi) * 2048);
    #pragma unroll
    for (int j = 0; j < NF; ++j) {
      __builtin_amdgcn_s_setprio(1);
      #pragma unroll
      for (int mi = 0; mi < 4; ++mi)
        #pragma unroll
        for (int ks = 0; ks < 2; ++ks)
          acc[4 + mi][j] = __builtin_amdgcn_mfma_f32_16x16x32_bf16(aF[mi][ks], bF[j][ks], acc[4 + mi][j], 0, 0, 0);
      __builtin_amdgcn_s_setprio(0);
    }

    __builtin_amdgcn_s_barrier();                // all waves done reading buf[cur]
    cur ^= 1;
  }

  // epilogue; C/D layout (m89-verified): col = lane&15, row = (lane>>4)*4 + reg
  #pragma unroll
  for (int mf = 0; mf < 8; ++mf) {
    #pragma unroll
    for (int nf = 0; nf < NF; ++nf) {
      const int row0 = m0 + wm * 128 + mf * 16 + kg * 4;
      const int colb = n0 + wn * (BNT / 4) + nf * 16;
      const int col = colb + rl;
      bool isV = false;
      if constexpr (ROPE) {
        if (colb >= VOFF) {
          // V column: write transposed to vt[(b*512 + vcol)][s], 4 consecutive s
          isV = true;
          const int vcol = col - VOFF;            // kvh*128 + d
          const int brow = row0 >> 11;            // batch (SEQ = 2048)
          const int s0v = row0 & (SEQ - 1);
          unsigned short* dst = vtO + (size_t)(brow * 512 + vcol) * SEQ + s0v;
          uint2 dw;
          dw.x = cvtpk_bf16(acc[mf][nf][0], acc[mf][nf][1]);
          dw.y = cvtpk_bf16(acc[mf][nf][2], acc[mf][nf][3]);
          *(uint2*)dst = dw;
        } else {
          // Q or K region: rotary (Q also * SM_L2)
          const int dd = (col & 127) >> 1;        // pair index within head
          const float sgn = (col & 1) ? 1.0f : -1.0f;
          const float qs = (colb < KOFF) ? SM_L2 : 1.0f;
          #pragma unroll
          for (int r = 0; r < 4; ++r) {
            const int s = (row0 + r) & (SEQ - 1);
            const float c = tc[s * 64 + dd], sn = ts[s * 64 + dd];
            const float xv = acc[mf][nf][r];
            const float xp = __shfl_xor(xv, 1);   // partner column (col^1)
            acc[mf][nf][r] = (xv * c + sgn * xp * sn) * qs;
          }
        }
      }
      if (!isV) {
        #pragma unroll
        for (int r = 0; r < 4; ++r) {
          if constexpr (OUTF32)
            ((float*)C)[(size_t)(row0 + r) * N + col] = acc[mf][nf][r];
          else
            ((unsigned short*)C)[(size_t)(row0 + r) * N + col] = f2bf(acc[mf][nf][r]);
        }
      }
    }
  }
}

// ---------------- flash attention, causal, GQA ------------------------------
// 8 waves x 16 q-rows (QB=128), KVBLK=64 DOUBLE-BUFFERED via GLL16 with counted
// vmcnt(4) + raw barriers (T3/T4); swapped QK^T -> lane-local softmax; P in LDS
// (XOR-swizzled, stride 64). LDS offsets hoisted (loop-invariant XOR keys).

constexpr int QB = 128, KB = 64;
constexpr float THR = 8.0f;                    // defer-max threshold (log2 domain)

__global__ __launch_bounds__(512, 4) void k_attn(const unsigned short* __restrict__ qkv,
                                                 const unsigned short* __restrict__ vt,
                                                 unsigned short* __restrict__ obuf) {
  __shared__ unsigned short Ks[2][KB * DH];     // 2 x [64][128], chunk-XOR ^(row&7)
  __shared__ unsigned short Vs[2][DH * KB];     // 2 x [128][64], chunk-XOR ^(row&7)
  __shared__ unsigned short Pw[8][16 * 64];     // per-wave P, stride 64, XOR ^(rl&7)<<4

  const int t = threadIdx.x, l = t & 63, w = t >> 6;
  const int rl = l & 15, kg = l >> 4;

  // complementary-pair decode: ids i and i+256 get q-tiles qt and 15-qt
  const int id = blockIdx.x;                    // [0, 512)
  const int b = id >> 8;
  const int u = id & 255;
  const int h = u >> 4;
  const int qtr = u & 15;
  const int qt = b ? (15 - qtr) : qtr;
  const int q0 = qt * QB;
  const int kvh = h >> 2;

  const unsigned short* qbase = qkv + (size_t)b * SEQ * NQKV;
  const unsigned short* kbase = qbase + KOFF + kvh * DH;
  const unsigned short* vtb = vt + (size_t)(b * NKVH + kvh) * DH * SEQ;

  // staging sources: K chunks c=i*512+t (row=c>>4, q=c&15); V chunks (row=c>>3, q=c&7)
  const unsigned short* kp[2];
  const unsigned short* vp[2];
  #pragma unroll
  for (int i = 0; i < 2; ++i) {
    int c = i * 512 + t;
    int krow = c >> 4, kq = c & 15;
    kp[i] = kbase + (size_t)krow * NQKV + ((kq ^ (krow & 7)) << 3);
    int vrow = c >> 3, vq = c & 7;
    vp[i] = vtb + (size_t)vrow * SEQ + ((vq ^ (vrow & 7)) << 3);
  }

  const int qw0 = q0 + w * 16;

  // Q fragments hoisted: lane holds Q[row=qw0+rl][k=kg*8+j], 4 k-steps
  short8 qF[4];
  {
    const size_t qr = (size_t)(qw0 + rl) * NQKV + h * DH;
    #pragma unroll
    for (int ks = 0; ks < 4; ++ks)
      qF[ks] = *(const short8*)(qbase + qr + ks * 32 + kg * 8);
  }

  // hoisted LDS byte offsets (loop-invariant)
  const int pkey = (rl & 7) << 4;
  int oK[4], oV[2], oPW[4], oPR[2];
  #pragma unroll
  for (int ks = 0; ks < 4; ++ks) oK[ks] = rl * 256 + (((ks * 4 + kg) << 4) ^ pkey);
  #pragma unroll
  for (int ks = 0; ks < 2; ++ks) oV[ks] = rl * 128 + (((ks * 4 + kg) << 4) ^ pkey);
  const int pwb = w * 2048 + rl * 128;
  #pragma unroll
  for (int n = 0; n < 4; ++n) oPW[n] = pwb + ((n * 32 + kg * 8) ^ pkey);
  #pragma unroll
  for (int ks = 0; ks < 2; ++ks) oPR[ks] = pwb + ((ks * 64 + kg * 16) ^ pkey);
  const char* KsB = (const char*)Ks;
  const char* VsB = (const char*)Vs;
  char* PwB = (char*)Pw;

  f32x4 Oc[8] = {};
  float mr = -3e38f, lr = 0.f;                  // per-lane state for q = qw0 + rl

  const int nt = q0 / KB + 2;                   // kv tiles up to (incl.) diagonal

  // prologue: stage tile 0 into buffer 0 (4 GLL16 / wave)
  #pragma unroll
  for (int i = 0; i < 2; ++i) {
    GLL16(kp[i], (char*)Ks[0] + w * 1024 + i * 8192);
    GLL16(vp[i], (char*)Vs[0] + w * 1024 + i * 8192);
  }

  int cur = 0;
  for (int tt = 0; tt < nt; ++tt) {
    const int kv0 = tt * KB;
    const bool more = (tt + 1 < nt);
    if (more) {                                  // issue next-tile loads into buf^1
      #pragma unroll
      for (int i = 0; i < 2; ++i) {
        GLL16(kp[i] + (size_t)(kv0 + KB) * NQKV, (char*)Ks[cur ^ 1] + w * 1024 + i * 8192);
        GLL16(vp[i] + (kv0 + KB),               (char*)Vs[cur ^ 1] + w * 1024 + i * 8192);
      }
      asm volatile("s_waitcnt vmcnt(4)" ::: "memory");   // tile tt's 4 loads landed
    } else {
      asm volatile("s_waitcnt vmcnt(0)" ::: "memory");
    }
    __builtin_amdgcn_sched_barrier(0);
    __builtin_amdgcn_s_barrier();                // all waves' tile-tt loads visible

    if (kv0 < qw0 + 16) {                        // not fully masked (wave-uniform)
      const int co = cur << 14;                  // cur * 16384 (per-buffer bytes)
      int cK[4] = { oK[0] + co, oK[1] + co, oK[2] + co, oK[3] + co };
      int cV[2] = { oV[0] + co, oV[1] + co };

      // S^T = K Q : lane (rl,kg) holds S[q=qw0+rl][kv = kv0 + n*16 + kg*4 + r]
      f32x4 St[4] = {};
      __builtin_amdgcn_s_setprio(1);
      #pragma unroll
      for (int n = 0; n < 4; ++n) {
        #pragma unroll
        for (int ks = 0; ks < 4; ++ks) {
          short8 kF = *(const short8*)(KsB + cK[ks] + n * 4096);
          St[n] = __builtin_amdgcn_mfma_f32_16x16x32_bf16(kF, qF[ks], St[n], 0, 0, 0);
        }
      }
      __builtin_amdgcn_s_setprio(0);

      // lane-local mask + max for q-row qw0+rl
      float mx = -3e38f;
      const bool diag = (kv0 + KB - 1) > qw0;    // tile straddles the diagonal
      if (diag) {
        const int thr = qw0 + rl - kv0;          // mask if kv-idx > thr
        #pragma unroll
        for (int n = 0; n < 4; ++n)
          #pragma unroll
          for (int r = 0; r < 4; ++r) {
            float s = St[n][r];
            if (n * 16 + kg * 4 + r > thr) s = -3e38f;
            St[n][r] = s;
            mx = fmaxf(mx, s);
          }
      } else {
        #pragma unroll
        for (int n = 0; n < 4; ++n)
          #pragma unroll
          for (int r = 0; r < 4; ++r) mx = fmaxf(mx, St[n][r]);
      }
      mx = fmaxf(mx, __shfl_xor(mx, 16));
      mx = fmaxf(mx, __shfl_xor(mx, 32));

      // deferred rescale (T13)
      if (__any(mx > mr + THR)) {
        const float mnew = fmaxf(mr, mx);
        const float sf = exp2f(mr - mnew);
        mr = mnew;
        lr *= sf;
        float sfv[4];
        #pragma unroll
        for (int r = 0; r < 4; ++r) sfv[r] = __shfl(sf, kg * 4 + r, 16);
        #pragma unroll
        for (int c = 0; c < 8; ++c)
          #pragma unroll
          for (int r = 0; r < 4; ++r) Oc[c][r] *= sfv[r];
      }

      // exp2 + pack (cvt_pk) + lane-local sum; P[q=rl][kv] -> LDS (XOR-swizzled)
      float rs = 0.f;
      #pragma unroll
      for (int n = 0; n < 4; ++n) {
        float e0 = exp2f(St[n][0] - mr);
        float e1 = exp2f(St[n][1] - mr);
        float e2 = exp2f(St[n][2] - mr);
        float e3 = exp2f(St[n][3] - mr);
        rs += (e0 + e1) + (e2 + e3);
        uint2 d;
        d.x = cvtpk_bf16(e0, e1);
        d.y = cvtpk_bf16(e2, e3);
        *(uint2*)(PwB + oPW[n]) = d;
      }
      rs += __shfl_xor(rs, 16);
      rs += __shfl_xor(rs, 32);
      lr += rs;

      // PV: A = P[16][64] (row=rl, k=kv), B = V (col=d, k=kv) from Vs rows
      short8 pF[2];
      #pragma unroll
      for (int ks2 = 0; ks2 < 2; ++ks2)
        pF[ks2] = *(const short8*)(PwB + oPR[ks2]);
      __builtin_amdgcn_s_setprio(1);
      #pragma unroll
      for (int c = 0; c < 8; ++c) {
        #pragma unroll
        for (int ks2 = 0; ks2 < 2; ++ks2) {
          short8 vF = *(const short8*)(VsB + cV[ks2] + c * 2048);
          Oc[c] = __builtin_amdgcn_mfma_f32_16x16x32_bf16(pF[ks2], vF, Oc[c], 0, 0, 0);
        }
      }
      __builtin_amdgcn_s_setprio(0);
    }

    __builtin_amdgcn_s_barrier();                // all waves done reading buf[cur]
    cur ^= 1;
  }

  // epilogue: O /= l (broadcast per output row), write bf16 [b*S+s][h*128+d]
  const float linv = 1.0f / lr;
  float inv[4];
  #pragma unroll
  for (int r = 0; r < 4; ++r) inv[r] = __shfl(linv, kg * 4 + r, 16);
  #pragma unroll
  for (int c = 0; c < 8; ++c)
    #pragma unroll
    for (int r = 0; r < 4; ++r) {
      int row = b * SEQ + qw0 + kg * 4 + r;
      obuf[(size_t)row * DMODEL + h * DH + c * 16 + rl] = f2bf(Oc[c][r] * inv[r]);
    }
}

// ---------------- launch ----------------------------------------------------

extern "C" void kernel_launch(void* const* d_in, const int* in_sizes, int n_in,
                              void* d_out, int out_size, void* d_ws, size_t ws_size,
                              hipStream_t stream) {
  const float* x  = (const float*)d_in[0];
  const float* wq = (const float*)d_in[1];
  const float* wk = (const float*)d_in[2];
  const float* wv = (const float*)d_in[3];
  const float* wo = (const float*)d_in[4];
  float* out = (float*)d_out;

  unsigned short* xb  = (unsigned short*)d_ws;                 // 4096x2048
  unsigned short* wT  = xb  + (size_t)MROWS * DMODEL;          // 3072x2048 (q|k|v transposed)
  unsigned short* woT = wT  + (size_t)NQKV * DMODEL;           // 2048x2048
  unsigned short* qkv = woT + (size_t)DMODEL * DMODEL;         // 4096x3072
  unsigned short* ob  = qkv + (size_t)MROWS * NQKV;            // 4096x2048
  float* tc = (float*)(ob + (size_t)MROWS * DMODEL);           // 2048x64
  float* ts = tc + SEQ * 64;
  // vt gets its OWN region (must not alias wT: GEMM epilogue writes vt while
  // other blocks still read wT): 2*4*128*2048 elems = 4 MB
  unsigned short* vtG = (unsigned short*)(ts + SEQ * 64);

  k_prep<<<dim3(MROWS * DMODEL / 4 / 256), dim3(256), 0, stream>>>(x, xb, tc, ts);
  k_wtrans4<<<dim3(64, 64, 4), dim3(32, 8), 0, stream>>>(wq, wk, wv, wo, wT, woT);

  // QKV: 4096x3072 = (16 x 16) tiles of 256x192 -> exactly 1 block/CU, no tail
  // (V columns stream directly to vtG transposed; k_vtrans eliminated)
  k_gemm256<192, false, true><<<dim3(NQKV / 192, MROWS / 256), dim3(512), 0, stream>>>(
      xb, wT, qkv, MROWS, NQKV, DMODEL, tc, ts, vtG);
  k_attn<<<dim3(512), dim3(512), 0, stream>>>(qkv, vtG, ob);
  k_gemm256<128, true, false><<<dim3(DMODEL / 128, MROWS / 256), dim3(512), 0, stream>>>(
      ob, woT, out, MROWS, DMODEL, DMODEL, nullptr, nullptr, nullptr);
}

// Round 18
// 206.511 us; speedup vs baseline: 1.3275x; 1.0133x over previous
//
#include <hip/hip_runtime.h>
#include <cstdint>
#include <cstddef>

using short8 = __attribute__((ext_vector_type(8))) short;
using f32x4  = __attribute__((ext_vector_type(4))) float;
using u16x4  = __attribute__((ext_vector_type(4))) unsigned short;

#define DEV __device__ __forceinline__

DEV unsigned short f2bf(float f) {
  unsigned int u = __builtin_bit_cast(unsigned int, f);
  u += 0x7fffu + ((u >> 16) & 1u);          // RNE
  return (unsigned short)(u >> 16);
}
DEV float bf2f(unsigned short h) {
  unsigned int u = ((unsigned int)h) << 16;
  return __builtin_bit_cast(float, u);
}
DEV unsigned int cvtpk_bf16(float lo, float hi) {  // d.lo16=bf16(lo), d.hi16=bf16(hi)
  unsigned int d;
  asm("v_cvt_pk_bf16_f32 %0, %1, %2" : "=v"(d) : "v"(lo), "v"(hi));
  return d;
}

// direct global->LDS, width 16B (m97 lever). LDS dest = wave-uniform base + lane*16.
#define GLL16(gp, lp)                                                          \
  __builtin_amdgcn_global_load_lds(                                            \
      (const __attribute__((address_space(1))) char*)(const char*)(gp),        \
      (__attribute__((address_space(3))) char*)(char*)(lp), 16, 0, 0)

constexpr int BATCH = 2, SEQ = 2048, DMODEL = 2048, NH = 16, NKVH = 4, DH = 128;
constexpr int MROWS = BATCH * SEQ;            // 4096
constexpr int NQKV  = DMODEL + 2 * NKVH * DH; // 3072 (Q | K | V)
constexpr int KOFF  = DMODEL;                 // 2048
constexpr int VOFF  = DMODEL + NKVH * DH;     // 2560
constexpr float SM_L2 = 0.12751388158f;       // (1/sqrt(128)) * log2(e), folded into Q

// ---------------- fused prep: weight transposes (z<4) + x-cast/tables (z>=4) --

__global__ __launch_bounds__(256) void k_prepw(
    const float* __restrict__ x, unsigned short* __restrict__ xb,
    float* __restrict__ tc, float* __restrict__ ts,
    const float* __restrict__ wq, const float* __restrict__ wk,
    const float* __restrict__ wv, const float* __restrict__ wo,
    unsigned short* __restrict__ wT, unsigned short* __restrict__ woT) {
  const int z = blockIdx.z;
  if (z >= 4) {
    // x fp32 -> bf16 cast + RoPE cos/sin tables (first 131072 ids)
    const int tid = threadIdx.y * 32 + threadIdx.x;
    const int id = (((z - 4) * 4096) + blockIdx.y * 64 + blockIdx.x) * 256 + tid;
    if (id < SEQ * 64) {
      int pos = id >> 6, i = id & 63;
      float freq = __expf(-(float)i * 0.14391157f);
      float ang = (float)pos * freq;
      tc[id] = cosf(ang);
      ts[id] = sinf(ang);
    }
    float4 v = ((const float4*)x)[id];
    u16x4 o = { f2bf(v.x), f2bf(v.y), f2bf(v.z), f2bf(v.w) };
    ((u16x4*)xb)[id] = o;
    return;
  }
  // weight transpose: z=0 wq->wT, z=1 wo->woT, z=2 wk, z=3 wv
  __shared__ float tile[32][33];
  const float* src; unsigned short* dst; int N;
  if (z == 0)      { src = wq; dst = wT;                        N = 2048; }
  else if (z == 1) { src = wo; dst = woT;                       N = 2048; }
  else if (z == 2) { src = wk; dst = wT + (size_t)KOFF * 2048;  N = 512; }
  else             { src = wv; dst = wT + (size_t)VOFF * 2048;  N = 512; }
  int n0 = blockIdx.x * 32, k0 = blockIdx.y * 32;
  if (n0 >= N) return;
  int tx = threadIdx.x, ty = threadIdx.y;     // 32 x 8
  #pragma unroll
  for (int r = ty; r < 32; r += 8)
    tile[r][tx] = src[(size_t)(k0 + r) * N + n0 + tx];
  __syncthreads();
  #pragma unroll
  for (int r = ty; r < 32; r += 8)
    dst[(size_t)(n0 + r) * 2048 + k0 + tx] = f2bf(tile[tx][r]);
}

// ---------------- big-tile GEMM: C[m][n] = sum_k A[m][k]*Bt[n][k] ------------
// 256xBNT tile (BNT in {128,192,256}), BK=64, 512 thr / 8 waves (2M x 4N),
// double-buffered LDS, counted vmcnt (T3/T4), ^(row&7) chunk swizzle (T2),
// setprio around MFMA clusters (T5). ROPE=true: rotary fused into epilogue for
// Q/K columns; V columns written TRANSPOSED to vtO ([b][kvh][d][s]) instead of
// C, eliminating the separate k_vtrans pass.

template <int BNT, bool OUTF32, bool ROPE>
__global__ __launch_bounds__(512, 2) void k_gemm256(
    const unsigned short* __restrict__ A,   // M x K bf16
    const unsigned short* __restrict__ Bt,  // N x K bf16
    void* __restrict__ C, int M, int N, int K,
    const float* __restrict__ tc, const float* __restrict__ ts,
    unsigned short* __restrict__ vtO) {
  constexpr int NF = BNT / 64;              // n-frags per wave (per-wave N = BNT/4)
  __shared__ unsigned short As[2][256 * 64];
  __shared__ unsigned short Bs[2][BNT * 64];

  const int t = threadIdx.x, l = t & 63, w = t >> 6;
  const int rl = l & 15, kg = l >> 4;
  const int wm = w >> 2, wn = w & 3;

  // XCD-aware swizzle (T1): nwg % 8 == 0 for all instantiations
  const int gx = gridDim.x;
  const int nwg = gx * gridDim.y;
  const int idl = blockIdx.y * gx + blockIdx.x;
  const int swz = (idl & 7) * (nwg >> 3) + (idl >> 3);
  const int m0 = (swz / gx) * 256, n0 = (swz % gx) * BNT;

  // staging sources (pre-swizzled: LDS dest linear, source permuted, read XOR'd)
  const unsigned short* aSrc[4];
  const unsigned short* bSrc[NF];
  #pragma unroll
  for (int i = 0; i < 4; ++i) {
    int c = i * 512 + t, row = c >> 3, q = c & 7;
    aSrc[i] = A + (size_t)(m0 + row) * K + ((q ^ (row & 7)) << 3);
  }
  #pragma unroll
  for (int i = 0; i < NF; ++i) {
    int c = i * 512 + t, row = c >> 3, q = c & 7;
    bSrc[i] = Bt + (size_t)(n0 + row) * K + ((q ^ (row & 7)) << 3);
  }

  // hoisted LDS read offsets (bytes): row&7 == rl&7 for all fragment rows
  const int pkey = (rl & 7) << 4;
  int oA[2], oB[2];
  #pragma unroll
  for (int ks = 0; ks < 2; ++ks) {
    oA[ks] = (wm * 128 + rl) * 128 + (((ks * 4 + kg) << 4) ^ pkey);
    oB[ks] = (wn * (BNT / 4) + rl) * 128 + (((ks * 4 + kg) << 4) ^ pkey);
  }
  const char* AsB = (const char*)As;
  const char* BsB = (const char*)Bs;

  f32x4 acc[8][NF] = {};

  const int nk = K / 64;
  // prologue: stage K-tile 0 into buffer 0
  #pragma unroll
  for (int i = 0; i < 4; ++i) GLL16(aSrc[i], (char*)As[0] + i * 8192 + t * 16);
  #pragma unroll
  for (int i = 0; i < NF; ++i) GLL16(bSrc[i], (char*)Bs[0] + i * 8192 + t * 16);

  int cur = 0;
  for (int kt = 0; kt < nk; ++kt) {
    if (kt + 1 < nk) {                           // issue next K-tile into buf^1
      const int off = (kt + 1) * 64;
      #pragma unroll
      for (int i = 0; i < 4; ++i)
        GLL16(aSrc[i] + off, (char*)As[cur ^ 1] + i * 8192 + t * 16);
      #pragma unroll
      for (int i = 0; i < NF; ++i)
        GLL16(bSrc[i] + off, (char*)Bs[cur ^ 1] + i * 8192 + t * 16);
      if constexpr (NF == 4)      asm volatile("s_waitcnt vmcnt(8)" ::: "memory");
      else if constexpr (NF == 3) asm volatile("s_waitcnt vmcnt(7)" ::: "memory");
      else                        asm volatile("s_waitcnt vmcnt(6)" ::: "memory");
    } else {
      asm volatile("s_waitcnt vmcnt(0)" ::: "memory");
    }
    __builtin_amdgcn_sched_barrier(0);
    __builtin_amdgcn_s_barrier();                // K-tile kt resident in buf[cur]

    const int coA = cur ? 32768 : 0;             // As per-buffer bytes
    const int coB = cur ? BNT * 128 : 0;         // Bs per-buffer bytes
    int cA[2] = { oA[0] + coA, oA[1] + coA };
    int cB[2] = { oB[0] + coB, oB[1] + coB };

    short8 aF[4][2], bF[NF][2];
    // A-half0 phases: per n-frag j, read bF[j] then 8 MFMA
    #pragma unroll
    for (int mi = 0; mi < 4; ++mi)
      #pragma unroll
      for (int ks = 0; ks < 2; ++ks)
        aF[mi][ks] = *(const short8*)(AsB + cA[ks] + mi * 2048);
    #pragma unroll
    for (int j = 0; j < NF; ++j) {
      #pragma unroll
      for (int ks = 0; ks < 2; ++ks)
        bF[j][ks] = *(const short8*)(BsB + cB[ks] + j * 2048);
      __builtin_amdgcn_s_setprio(1);
      #pragma unroll
      for (int mi = 0; mi < 4; ++mi)
        #pragma unroll
        for (int ks = 0; ks < 2; ++ks)
          acc[mi][j] = __builtin_amdgcn_mfma_f32_16x16x32_bf16(aF[mi][ks], bF[j][ks], acc[mi][j], 0, 0, 0);
      __builtin_amdgcn_s_setprio(0);
    }
    // A-half1 phases (bF already live)
    #pragma unroll
    for (int mi = 0; mi < 4; ++mi)
      #pragma unroll
      for (int ks = 0; ks < 2; ++ks)
        aF[mi][ks] = *(const short8*)(AsB + cA[ks] + (4 + mi) * 2048);
    #pragma unroll
    for (int j = 0; j < NF; ++j) {
      __builtin_amdgcn_s_setprio(1);
      #pragma unroll
      for (int mi = 0; mi < 4; ++mi)
        #pragma unroll
        for (int ks = 0; ks < 2; ++ks)
          acc[4 + mi][j] = __builtin_amdgcn_mfma_f32_16x16x32_bf16(aF[mi][ks], bF[j][ks], acc[4 + mi][j], 0, 0, 0);
      __builtin_amdgcn_s_setprio(0);
    }

    __builtin_amdgcn_s_barrier();                // all waves done reading buf[cur]
    cur ^= 1;
  }

  // epilogue; C/D layout (m89-verified): col = lane&15, row = (lane>>4)*4 + reg
  #pragma unroll
  for (int mf = 0; mf < 8; ++mf) {
    #pragma unroll
    for (int nf = 0; nf < NF; ++nf) {
      const int row0 = m0 + wm * 128 + mf * 16 + kg * 4;
      const int colb = n0 + wn * (BNT / 4) + nf * 16;
      const int col = colb + rl;
      bool isV = false;
      if constexpr (ROPE) {
        if (colb >= VOFF) {
          // V column: write transposed to vt[(b*512 + vcol)][s], 4 consecutive s
          isV = true;
          const int vcol = col - VOFF;            // kvh*128 + d
          const int brow = row0 >> 11;            // batch (SEQ = 2048)
          const int s0v = row0 & (SEQ - 1);
          unsigned short* dst = vtO + (size_t)(brow * 512 + vcol) * SEQ + s0v;
          uint2 dw;
          dw.x = cvtpk_bf16(acc[mf][nf][0], acc[mf][nf][1]);
          dw.y = cvtpk_bf16(acc[mf][nf][2], acc[mf][nf][3]);
          *(uint2*)dst = dw;
        } else {
          // Q or K region: rotary (Q also * SM_L2)
          const int dd = (col & 127) >> 1;        // pair index within head
          const float sgn = (col & 1) ? 1.0f : -1.0f;
          const float qs = (colb < KOFF) ? SM_L2 : 1.0f;
          #pragma unroll
          for (int r = 0; r < 4; ++r) {
            const int s = (row0 + r) & (SEQ - 1);
            const float c = tc[s * 64 + dd], sn = ts[s * 64 + dd];
            const float xv = acc[mf][nf][r];
            const float xp = __shfl_xor(xv, 1);   // partner column (col^1)
            acc[mf][nf][r] = (xv * c + sgn * xp * sn) * qs;
          }
        }
      }
      if (!isV) {
        #pragma unroll
        for (int r = 0; r < 4; ++r) {
          if constexpr (OUTF32)
            ((float*)C)[(size_t)(row0 + r) * N + col] = acc[mf][nf][r];
          else
            ((unsigned short*)C)[(size_t)(row0 + r) * N + col] = f2bf(acc[mf][nf][r]);
        }
      }
    }
  }
}

// ---------------- flash attention, causal, GQA ------------------------------
// 8 waves x 16 q-rows (QB=128), KVBLK=64 DOUBLE-BUFFERED via GLL16 with counted
// vmcnt(4) + raw barriers (T3/T4); swapped QK^T -> lane-local softmax; P in LDS
// (XOR-swizzled, stride 64). LDS offsets hoisted (loop-invariant XOR keys).

constexpr int QB = 128, KB = 64;
constexpr float THR = 8.0f;                    // defer-max threshold (log2 domain)

__global__ __launch_bounds__(512, 4) void k_attn(const unsigned short* __restrict__ qkv,
                                                 const unsigned short* __restrict__ vt,
                                                 unsigned short* __restrict__ obuf) {
  __shared__ unsigned short Ks[2][KB * DH];     // 2 x [64][128], chunk-XOR ^(row&7)
  __shared__ unsigned short Vs[2][DH * KB];     // 2 x [128][64], chunk-XOR ^(row&7)
  __shared__ unsigned short Pw[8][16 * 64];     // per-wave P, stride 64, XOR ^(rl&7)<<4

  const int t = threadIdx.x, l = t & 63, w = t >> 6;
  const int rl = l & 15, kg = l >> 4;

  // complementary-pair decode: ids i and i+256 get q-tiles qt and 15-qt
  const int id = blockIdx.x;                    // [0, 512)
  const int b = id >> 8;
  const int u = id & 255;
  const int h = u >> 4;
  const int qtr = u & 15;
  const int qt = b ? (15 - qtr) : qtr;
  const int q0 = qt * QB;
  const int kvh = h >> 2;

  const unsigned short* qbase = qkv + (size_t)b * SEQ * NQKV;
  const unsigned short* kbase = qbase + KOFF + kvh * DH;
  const unsigned short* vtb = vt + (size_t)(b * NKVH + kvh) * DH * SEQ;

  // staging sources: K chunks c=i*512+t (row=c>>4, q=c&15); V chunks (row=c>>3, q=c&7)
  const unsigned short* kp[2];
  const unsigned short* vp[2];
  #pragma unroll
  for (int i = 0; i < 2; ++i) {
    int c = i * 512 + t;
    int krow = c >> 4, kq = c & 15;
    kp[i] = kbase + (size_t)krow * NQKV + ((kq ^ (krow & 7)) << 3);
    int vrow = c >> 3, vq = c & 7;
    vp[i] = vtb + (size_t)vrow * SEQ + ((vq ^ (vrow & 7)) << 3);
  }

  const int qw0 = q0 + w * 16;

  // Q fragments hoisted: lane holds Q[row=qw0+rl][k=kg*8+j], 4 k-steps
  short8 qF[4];
  {
    const size_t qr = (size_t)(qw0 + rl) * NQKV + h * DH;
    #pragma unroll
    for (int ks = 0; ks < 4; ++ks)
      qF[ks] = *(const short8*)(qbase + qr + ks * 32 + kg * 8);
  }

  // hoisted LDS byte offsets (loop-invariant)
  const int pkey = (rl & 7) << 4;
  int oK[4], oV[2], oPW[4], oPR[2];
  #pragma unroll
  for (int ks = 0; ks < 4; ++ks) oK[ks] = rl * 256 + (((ks * 4 + kg) << 4) ^ pkey);
  #pragma unroll
  for (int ks = 0; ks < 2; ++ks) oV[ks] = rl * 128 + (((ks * 4 + kg) << 4) ^ pkey);
  const int pwb = w * 2048 + rl * 128;
  #pragma unroll
  for (int n = 0; n < 4; ++n) oPW[n] = pwb + ((n * 32 + kg * 8) ^ pkey);
  #pragma unroll
  for (int ks = 0; ks < 2; ++ks) oPR[ks] = pwb + ((ks * 64 + kg * 16) ^ pkey);
  const char* KsB = (const char*)Ks;
  const char* VsB = (const char*)Vs;
  char* PwB = (char*)Pw;

  f32x4 Oc[8] = {};
  float mr = -3e38f, lr = 0.f;                  // per-lane state for q = qw0 + rl

  const int nt = q0 / KB + 2;                   // kv tiles up to (incl.) diagonal

  // prologue: stage tile 0 into buffer 0 (4 GLL16 / wave)
  #pragma unroll
  for (int i = 0; i < 2; ++i) {
    GLL16(kp[i], (char*)Ks[0] + w * 1024 + i * 8192);
    GLL16(vp[i], (char*)Vs[0] + w * 1024 + i * 8192);
  }

  int cur = 0;
  for (int tt = 0; tt < nt; ++tt) {
    const int kv0 = tt * KB;
    const bool more = (tt + 1 < nt);
    if (more) {                                  // issue next-tile loads into buf^1
      #pragma unroll
      for (int i = 0; i < 2; ++i) {
        GLL16(kp[i] + (size_t)(kv0 + KB) * NQKV, (char*)Ks[cur ^ 1] + w * 1024 + i * 8192);
        GLL16(vp[i] + (kv0 + KB),               (char*)Vs[cur ^ 1] + w * 1024 + i * 8192);
      }
      asm volatile("s_waitcnt vmcnt(4)" ::: "memory");   // tile tt's 4 loads landed
    } else {
      asm volatile("s_waitcnt vmcnt(0)" ::: "memory");
    }
    __builtin_amdgcn_sched_barrier(0);
    __builtin_amdgcn_s_barrier();                // all waves' tile-tt loads visible

    if (kv0 < qw0 + 16) {                        // not fully masked (wave-uniform)
      const int co = cur << 14;                  // cur * 16384 (per-buffer bytes)
      int cK[4] = { oK[0] + co, oK[1] + co, oK[2] + co, oK[3] + co };
      int cV[2] = { oV[0] + co, oV[1] + co };

      // S^T = K Q : lane (rl,kg) holds S[q=qw0+rl][kv = kv0 + n*16 + kg*4 + r]
      f32x4 St[4] = {};
      __builtin_amdgcn_s_setprio(1);
      #pragma unroll
      for (int n = 0; n < 4; ++n) {
        #pragma unroll
        for (int ks = 0; ks < 4; ++ks) {
          short8 kF = *(const short8*)(KsB + cK[ks] + n * 4096);
          St[n] = __builtin_amdgcn_mfma_f32_16x16x32_bf16(kF, qF[ks], St[n], 0, 0, 0);
        }
      }
      __builtin_amdgcn_s_setprio(0);

      // lane-local mask + max for q-row qw0+rl
      float mx = -3e38f;
      const bool diag = (kv0 + KB - 1) > qw0;    // tile straddles the diagonal
      if (diag) {
        const int thr = qw0 + rl - kv0;          // mask if kv-idx > thr
        #pragma unroll
        for (int n = 0; n < 4; ++n)
          #pragma unroll
          for (int r = 0; r < 4; ++r) {
            float s = St[n][r];
            if (n * 16 + kg * 4 + r > thr) s = -3e38f;
            St[n][r] = s;
            mx = fmaxf(mx, s);
          }
      } else {
        #pragma unroll
        for (int n = 0; n < 4; ++n)
          #pragma unroll
          for (int r = 0; r < 4; ++r) mx = fmaxf(mx, St[n][r]);
      }
      mx = fmaxf(mx, __shfl_xor(mx, 16));
      mx = fmaxf(mx, __shfl_xor(mx, 32));

      // deferred rescale (T13)
      if (__any(mx > mr + THR)) {
        const float mnew = fmaxf(mr, mx);
        const float sf = exp2f(mr - mnew);
        mr = mnew;
        lr *= sf;
        float sfv[4];
        #pragma unroll
        for (int r = 0; r < 4; ++r) sfv[r] = __shfl(sf, kg * 4 + r, 16);
        #pragma unroll
        for (int c = 0; c < 8; ++c)
          #pragma unroll
          for (int r = 0; r < 4; ++r) Oc[c][r] *= sfv[r];
      }

      // exp2 + pack (cvt_pk) + lane-local sum; P[q=rl][kv] -> LDS (XOR-swizzled)
      float rs = 0.f;
      #pragma unroll
      for (int n = 0; n < 4; ++n) {
        float e0 = exp2f(St[n][0] - mr);
        float e1 = exp2f(St[n][1] - mr);
        float e2 = exp2f(St[n][2] - mr);
        float e3 = exp2f(St[n][3] - mr);
        rs += (e0 + e1) + (e2 + e3);
        uint2 d;
        d.x = cvtpk_bf16(e0, e1);
        d.y = cvtpk_bf16(e2, e3);
        *(uint2*)(PwB + oPW[n]) = d;
      }
      rs += __shfl_xor(rs, 16);
      rs += __shfl_xor(rs, 32);
      lr += rs;

      // PV: A = P[16][64] (row=rl, k=kv), B = V (col=d, k=kv) from Vs rows
      short8 pF[2];
      #pragma unroll
      for (int ks2 = 0; ks2 < 2; ++ks2)
        pF[ks2] = *(const short8*)(PwB + oPR[ks2]);
      __builtin_amdgcn_s_setprio(1);
      #pragma unroll
      for (int c = 0; c < 8; ++c) {
        #pragma unroll
        for (int ks2 = 0; ks2 < 2; ++ks2) {
          short8 vF = *(const short8*)(VsB + cV[ks2] + c * 2048);
          Oc[c] = __builtin_amdgcn_mfma_f32_16x16x32_bf16(pF[ks2], vF, Oc[c], 0, 0, 0);
        }
      }
      __builtin_amdgcn_s_setprio(0);
    }

    __builtin_amdgcn_s_barrier();                // all waves done reading buf[cur]
    cur ^= 1;
  }

  // epilogue: O /= l (broadcast per output row), write bf16 [b*S+s][h*128+d]
  const float linv = 1.0f / lr;
  float inv[4];
  #pragma unroll
  for (int r = 0; r < 4; ++r) inv[r] = __shfl(linv, kg * 4 + r, 16);
  #pragma unroll
  for (int c = 0; c < 8; ++c)
    #pragma unroll
    for (int r = 0; r < 4; ++r) {
      int row = b * SEQ + qw0 + kg * 4 + r;
      obuf[(size_t)row * DMODEL + h * DH + c * 16 + rl] = f2bf(Oc[c][r] * inv[r]);
    }
}

// ---------------- launch ----------------------------------------------------

extern "C" void kernel_launch(void* const* d_in, const int* in_sizes, int n_in,
                              void* d_out, int out_size, void* d_ws, size_t ws_size,
                              hipStream_t stream) {
  const float* x  = (const float*)d_in[0];
  const float* wq = (const float*)d_in[1];
  const float* wk = (const float*)d_in[2];
  const float* wv = (const float*)d_in[3];
  const float* wo = (const float*)d_in[4];
  float* out = (float*)d_out;

  unsigned short* xb  = (unsigned short*)d_ws;                 // 4096x2048
  unsigned short* wT  = xb  + (size_t)MROWS * DMODEL;          // 3072x2048 (q|k|v transposed)
  unsigned short* woT = wT  + (size_t)NQKV * DMODEL;           // 2048x2048
  unsigned short* qkv = woT + (size_t)DMODEL * DMODEL;         // 4096x3072
  unsigned short* ob  = qkv + (size_t)MROWS * NQKV;            // 4096x2048
  float* tc = (float*)(ob + (size_t)MROWS * DMODEL);           // 2048x64
  float* ts = tc + SEQ * 64;
  // vt: own region (GEMM epilogue writes it while other blocks read wT)
  unsigned short* vtG = (unsigned short*)(ts + SEQ * 64);      // 4 MB

  // fused prep: z<4 weight transposes, z>=4 x-cast + tables (8192 eff. blocks)
  k_prepw<<<dim3(64, 64, 6), dim3(32, 8), 0, stream>>>(
      x, xb, tc, ts, wq, wk, wv, wo, wT, woT);

  // QKV: 4096x3072 = (16 x 16) tiles of 256x192 -> exactly 1 block/CU, no tail
  // (V columns stream directly to vtG transposed)
  k_gemm256<192, false, true><<<dim3(NQKV / 192, MROWS / 256), dim3(512), 0, stream>>>(
      xb, wT, qkv, MROWS, NQKV, DMODEL, tc, ts, vtG);
  k_attn<<<dim3(512), dim3(512), 0, stream>>>(qkv, vtG, ob);
  k_gemm256<128, true, false><<<dim3(DMODEL / 128, MROWS / 256), dim3(512), 0, stream>>>(
      ob, woT, out, MROWS, DMODEL, DMODEL, nullptr, nullptr, nullptr);
}